// Round 4
// baseline (473.790 us; speedup 1.0000x reference)
//
#include <hip/hip_runtime.h>

typedef unsigned short u16;
typedef unsigned int u32;
typedef _Float16 f16;
typedef f16 f16x8 __attribute__((ext_vector_type(8)));
typedef float f32x4 __attribute__((ext_vector_type(4)));

__device__ __forceinline__ float h2f(f16 h){ return (float)h; }
__device__ __forceinline__ f16 f2h(float f){ return (f16)f; }

__device__ __forceinline__ f16x8 ldfrag(const f16* p){
  union { uint4 u; f16x8 h; } x;
  x.u = *(const uint4*)p;
  return x.h;
}
__device__ __forceinline__ void gload_lds16(const f16* g, f16* l){
  __builtin_amdgcn_global_load_lds(
      (const __attribute__((address_space(1))) u32*)g,
      (__attribute__((address_space(3))) u32*)l, 16, 0, 0);
}

// ---------------- CSR build ----------------

__global__ void detect_kernel(const int* __restrict__ ei, int* __restrict__ flag){
  if (threadIdx.x == 0 && blockIdx.x == 0){
    int orv = 0;
    for (int i = 0; i < 200; i++) orv |= ei[2*i + 1];
    *flag = (orv == 0) ? 1 : 0;
  }
}

__global__ void init_kernel(int* __restrict__ cnt, int* __restrict__ fillpos, int n){
  int i = blockIdx.x * blockDim.x + threadIdx.x;
  if (i < n){ cnt[i] = 1; fillpos[i] = 1; } // slot 0 = self loop
}

__global__ void count_edges(const int* __restrict__ ei, int E, const int* __restrict__ flag,
                            int* __restrict__ cnt){
  int e = blockIdx.x * blockDim.x + threadIdx.x;
  if (e >= E) return;
  int dst = (*flag) ? ei[2*E + 2*e] : ei[E + e];
  atomicAdd(&cnt[dst], 1);
}

#define SCAN_T 1024
__global__ void scan_kernel(const int* __restrict__ cnt, int* __restrict__ row_ptr, int n){
  __shared__ int sm[SCAN_T];
  int t = threadIdx.x;
  int chunk = (n + SCAN_T - 1) / SCAN_T;
  int lo = t * chunk, hi = lo + chunk; if (hi > n) hi = n; if (lo > n) lo = n;
  int s = 0;
  for (int i = lo; i < hi; i++) s += cnt[i];
  sm[t] = s; __syncthreads();
  for (int off = 1; off < SCAN_T; off <<= 1){
    int v = (t >= off) ? sm[t - off] : 0;
    __syncthreads();
    sm[t] += v;
    __syncthreads();
  }
  int base = sm[t] - s;
  for (int i = lo; i < hi; i++){ row_ptr[i] = base; base += cnt[i]; }
  if (t == 0) row_ptr[n] = sm[SCAN_T - 1];
}

__global__ void selfloop_kernel(const int* __restrict__ row_ptr, int* __restrict__ col, int n){
  int i = blockIdx.x * blockDim.x + threadIdx.x;
  if (i < n) col[row_ptr[i]] = i;
}

__global__ void fill_edges(const int* __restrict__ ei, int E, const int* __restrict__ flag,
                           const int* __restrict__ row_ptr, int* __restrict__ fillpos,
                           int* __restrict__ col){
  int e = blockIdx.x * blockDim.x + threadIdx.x;
  if (e >= E) return;
  int f = *flag;
  int src = f ? ei[2*e]       : ei[e];
  int dst = f ? ei[2*E + 2*e] : ei[E + e];
  int off = atomicAdd(&fillpos[dst], 1);
  col[row_ptr[dst] + off] = src;
}

// ---------------- converts ----------------

__global__ void convert_f16(const float* __restrict__ X, f16* __restrict__ Xo, long n){
  long i = blockIdx.x * (long)blockDim.x + threadIdx.x;
  if (i >= n) return;
  Xo[i] = f2h(X[i]);
}

// W [K][N] fp32 -> WT [N][K] fp16 (tiled transpose)
__global__ void convert_wT(const float* __restrict__ W, f16* __restrict__ T, int K, int N){
  __shared__ float sm[32][33];
  int kb = blockIdx.x * 32, nb = blockIdx.y * 32;
  int tx = threadIdx.x, ty = threadIdx.y; // (32,8)
  for (int i = 0; i < 32; i += 8)
    sm[ty + i][tx] = W[(size_t)(kb + ty + i) * N + nb + tx];
  __syncthreads();
  for (int i = 0; i < 32; i += 8)
    T[(size_t)(nb + ty + i) * K + kb + tx] = f2h(sm[tx][ty + i]);
}

// ---------------- fp16 MFMA GEMM, 2-phase double-buffered ----------------
// C[M][N] = A[M][K] @ B[K][N]; A row-major fp16, B as WT[N][K] fp16.
// Tile 128 x (FJ*32); 4 waves 2x2; wave = 64 rows x FJ*16 cols; BK=32.
// EPI 0: fp32 C.  EPI 1: bias+lrelu -> fp16.  EPI 2: plain fp16.
// FA: fused alpha_src/dst = rowwise dot with flat a_s[n]/a_d[n], atomicAdd.

template<int EPI, int FJ, bool FA>
__global__ __launch_bounds__(256) void gemm_kernel(
    const f16* __restrict__ A, const f16* __restrict__ B,
    float* __restrict__ C, f16* __restrict__ Ch,
    const float* __restrict__ bias,
    const float* __restrict__ asf, const float* __restrict__ adf,
    float* __restrict__ asrc, float* __restrict__ adst, int HEADS, int CH,
    int M, int N, int K, int nbm, int nbn)
{
  constexpr int BN = FJ * 32;
  __shared__ f16 sA[2][128 * 32];
  __shared__ f16 sB[2][BN * 32];

  // bijective XCD swizzle (m204)
  int nwg = nbm * nbn;
  int bid = blockIdx.x;
  int q = nwg >> 3, r = nwg & 7;
  int xcd = bid & 7, idx = bid >> 3;
  int wg = (xcd < r ? xcd * (q + 1) : r * (q + 1) + (xcd - r) * q) + idx;
  int bm = wg / nbn, bn = wg % nbn;

  int tid = threadIdx.x;
  int lane = tid & 63;
  int w = tid >> 6;
  int wr = (w >> 1) * 64, wc = (w & 1) * (FJ * 16);
  int lm = lane & 15, lk = (lane >> 4) * 8;

  int sk = (tid & 3) * 8;
  long ar0 = (long)bm * 128 + (tid >> 2);
  long ar1 = ar0 + 64;
  if (ar0 >= M) ar0 = M - 1;   // clamped rows only feed unstored outputs
  if (ar1 >= M) ar1 = M - 1;
  long br0 = (long)bn * BN + (tid >> 2);  // N multiple of BN
  long br1 = br0 + 64;                    // used only when FJ==4

  const f16* pA0 = A + ar0 * K + sk;
  const f16* pA1 = A + ar1 * K + sk;
  const f16* pB0 = B + br0 * K + sk;
  const f16* pB1 = (FJ == 4) ? (B + br1 * K + sk) : pB0;
  const int d1 = 2048;  // 64 rows * 32 elems

  auto STAGE = [&](int buf, int k0){
    gload_lds16(pA0 + k0, &sA[buf][tid * 8]);
    gload_lds16(pA1 + k0, &sA[buf][d1 + tid * 8]);
    gload_lds16(pB0 + k0, &sB[buf][tid * 8]);
    if constexpr (FJ == 4)
      gload_lds16(pB1 + k0, &sB[buf][d1 + tid * 8]);
  };

  f32x4 acc[4][FJ] = {};

  int nt = K >> 5;
  STAGE(0, 0);
  __syncthreads();          // vmcnt(0) drain + barrier: buf0 ready
  int cur = 0;
  for (int t = 0; t < nt; t++){
    if (t + 1 < nt) STAGE(cur ^ 1, (t + 1) * 32);   // overlap with compute
    f16x8 af[4], bfr[FJ];
    #pragma unroll
    for (int f = 0; f < 4; f++)
      af[f] = ldfrag(&sA[cur][(wr + f * 16 + lm) * 32 + lk]);
    #pragma unroll
    for (int f = 0; f < FJ; f++)
      bfr[f] = ldfrag(&sB[cur][(wc + f * 16 + lm) * 32 + lk]);
    #pragma unroll
    for (int fi = 0; fi < 4; fi++)
      #pragma unroll
      for (int fj = 0; fj < FJ; fj++)
        acc[fi][fj] = __builtin_amdgcn_mfma_f32_16x16x32_f16(af[fi], bfr[fj], acc[fi][fj], 0, 0, 0);
    __syncthreads();        // drains next-tile loads; all waves done with cur
    cur ^= 1;
  }

  // ---- store epilogue ----
  #pragma unroll
  for (int fi = 0; fi < 4; fi++){
    int mb = bm * 128 + wr + fi * 16 + ((lane >> 4) << 2);
    #pragma unroll
    for (int fj = 0; fj < FJ; fj++){
      int n = bn * BN + wc + fj * 16 + lm;
      #pragma unroll
      for (int j = 0; j < 4; j++){
        int m = mb + j;
        if (m < M){
          float v = acc[fi][fj][j];
          size_t o = (size_t)m * N + n;
          if (EPI == 0){
            C[o] = v;
          } else if (EPI == 2){
            Ch[o] = f2h(v);
          } else {
            v += bias[n];
            v = v > 0.0f ? v : 0.2f * v;
            Ch[o] = f2h(v);
          }
        }
      }
    }
  }

  // ---- fused alpha epilogue ----
  if constexpr (FA){
    int hd = (bn * BN) / CH;      // block lies within one head band
    #pragma unroll
    for (int fi = 0; fi < 4; fi++){
      int mb = bm * 128 + wr + fi * 16 + ((lane >> 4) << 2);
      #pragma unroll
      for (int j = 0; j < 4; j++){
        float pa = 0.0f, pd = 0.0f;
        #pragma unroll
        for (int fj = 0; fj < FJ; fj++){
          int n = bn * BN + wc + fj * 16 + lm;
          float v = acc[fi][fj][j];
          pa += v * asf[n];
          pd += v * adf[n];
        }
        #pragma unroll
        for (int mk = 1; mk < 16; mk <<= 1){
          pa += __shfl_xor(pa, mk);
          pd += __shfl_xor(pd, mk);
        }
        int m = mb + j;
        if ((lane & 15) == 0 && m < M){
          atomicAdd(&asrc[m * HEADS + hd], pa);
          atomicAdd(&adst[m * HEADS + hd], pd);
        }
      }
    }
  }
}

// ---------------- edge softmax ----------------

template<int HEADS>
__global__ __launch_bounds__(256) void softmax_kernel(
    const int* __restrict__ row_ptr, const int* __restrict__ col,
    const float* __restrict__ asrc, const float* __restrict__ adst,
    float* __restrict__ alpha, int Nn)
{
  int dst = blockIdx.x * 4 + (threadIdx.x >> 6);
  int lane = threadIdx.x & 63;
  if (dst >= Nn) return;
  const int hd = (HEADS == 8) ? (lane & 7) : 0;
  const int el = (HEADS == 8) ? (lane >> 3) : lane;
  const int EPP = 64 / HEADS;
  int s = row_ptr[dst], e = row_ptr[dst + 1];
  float ad = adst[dst * HEADS + hd];
  float m = -1e30f;
  for (int p = s + el; p < e; p += EPP){
    float v = asrc[col[p] * HEADS + hd] + ad;
    v = v > 0.0f ? v : 0.2f * v;
    m = fmaxf(m, v);
  }
  for (int off = HEADS; off < 64; off <<= 1) m = fmaxf(m, __shfl_xor(m, off));
  float sum = 0.0f;
  for (int p = s + el; p < e; p += EPP){
    float v = asrc[col[p] * HEADS + hd] + ad;
    v = v > 0.0f ? v : 0.2f * v;
    sum += __expf(v - m);
  }
  for (int off = HEADS; off < 64; off <<= 1) sum += __shfl_xor(sum, off);
  float inv = 1.0f / (sum + 1e-16f);
  for (int p = s + el; p < e; p += EPP){
    float v = asrc[col[p] * HEADS + hd] + ad;
    v = v > 0.0f ? v : 0.2f * v;
    alpha[p * HEADS + hd] = __expf(v - m) * inv;
  }
}

// ---------------- aggregation (4-edge unrolled gather) ----------------

template<int F, int CH, bool FINAL, bool HF>
__global__ __launch_bounds__(256) void agg_kernel(
    const void* __restrict__ Hv, const float* __restrict__ alpha,
    const int* __restrict__ row_ptr, const int* __restrict__ col,
    const float* __restrict__ bias,
    f16* __restrict__ Oh, float* __restrict__ Ofp)
{
  constexpr int CPT = F / 256;
  constexpr int HEADS = F / CH;
  int dst = blockIdx.x;
  int t = threadIdx.x;
  int c0 = t * CPT;
  int hd = c0 / CH;
  float acc[CPT] = {};
  int s = row_ptr[dst], e = row_ptr[dst + 1];
  int p = s;

  if (HF){
    const f16* hb = (const f16*)Hv;
    for (; p + 4 <= e; p += 4){
      int s0 = col[p], s1 = col[p+1], s2 = col[p+2], s3 = col[p+3];
      float a0 = alpha[(p+0) * HEADS + hd];
      float a1 = alpha[(p+1) * HEADS + hd];
      float a2 = alpha[(p+2) * HEADS + hd];
      float a3 = alpha[(p+3) * HEADS + hd];
      union { uint4 u; f16 h[8]; } x0, x1, x2, x3;
      x0.u = *(const uint4*)(hb + (size_t)s0 * F + c0);
      x1.u = *(const uint4*)(hb + (size_t)s1 * F + c0);
      x2.u = *(const uint4*)(hb + (size_t)s2 * F + c0);
      x3.u = *(const uint4*)(hb + (size_t)s3 * F + c0);
      #pragma unroll
      for (int i = 0; i < 8; i++)
        acc[i] += a0 * h2f(x0.h[i]) + a1 * h2f(x1.h[i])
                + a2 * h2f(x2.h[i]) + a3 * h2f(x3.h[i]);
    }
    for (; p < e; p++){
      int src = col[p];
      float al = alpha[p * HEADS + hd];
      union { uint4 u; f16 h[8]; } x;
      x.u = *(const uint4*)(hb + (size_t)src * F + c0);
      #pragma unroll
      for (int i = 0; i < 8; i++) acc[i] += al * h2f(x.h[i]);
    }
  } else {
    const float* hb = (const float*)Hv;
    for (; p + 4 <= e; p += 4){
      int s0 = col[p], s1 = col[p+1], s2 = col[p+2], s3 = col[p+3];
      float a0 = alpha[(p+0) * HEADS + hd];
      float a1 = alpha[(p+1) * HEADS + hd];
      float a2 = alpha[(p+2) * HEADS + hd];
      float a3 = alpha[(p+3) * HEADS + hd];
      float2 v0 = *(const float2*)(hb + (size_t)s0 * F + c0);
      float2 v1 = *(const float2*)(hb + (size_t)s1 * F + c0);
      float2 v2 = *(const float2*)(hb + (size_t)s2 * F + c0);
      float2 v3 = *(const float2*)(hb + (size_t)s3 * F + c0);
      acc[0] += a0 * v0.x + a1 * v1.x + a2 * v2.x + a3 * v3.x;
      acc[1] += a0 * v0.y + a1 * v1.y + a2 * v2.y + a3 * v3.y;
    }
    for (; p < e; p++){
      int src = col[p];
      float al = alpha[p * HEADS + hd];
      float2 v = *(const float2*)(hb + (size_t)src * F + c0);
      acc[0] += al * v.x; acc[1] += al * v.y;
    }
  }

  #pragma unroll
  for (int i = 0; i < CPT; i++){
    float v = acc[i] + bias[c0 + i];
    v = v > 0.0f ? v : 0.2f * v;
    size_t o = (size_t)dst * F + c0 + i;
    if (FINAL) Ofp[o] = v;
    else       Oh[o]  = f2h(v);
  }
}

// ---------------- launcher ----------------

extern "C" void kernel_launch(void* const* d_in, const int* in_sizes, int n_in,
                              void* d_out, int out_size, void* d_ws, size_t ws_size,
                              hipStream_t stream)
{
  const float* x    = (const float*)d_in[0];
  const int*   ei   = (const int*)d_in[1];
  const float* W_in = (const float*)d_in[2];
  const float* b_in = (const float*)d_in[3];
  const float* W1   = (const float*)d_in[4];
  const float* as1  = (const float*)d_in[5];
  const float* ad1  = (const float*)d_in[6];
  const float* b1   = (const float*)d_in[7];
  const float* W2   = (const float*)d_in[8];
  const float* as2  = (const float*)d_in[9];
  const float* ad2  = (const float*)d_in[10];
  const float* b2   = (const float*)d_in[11];
  const float* W3   = (const float*)d_in[12];
  const float* as3  = (const float*)d_in[13];
  const float* ad3  = (const float*)d_in[14];
  const float* b3   = (const float*)d_in[15];

  const int N  = in_sizes[0] / 32;   // 10000
  const int E  = in_sizes[1] / 2;    // 80000
  const int ET = E + N;

  char* w = (char*)d_ws;
  size_t off = 0;
  auto carve = [&](size_t bytes) -> char* {
    off = (off + 255) & ~(size_t)255;
    char* p = w + off;
    off += bytes;
    return p;
  };

  int* flag    = (int*)carve(4);
  int* cnt     = (int*)carve((size_t)N * 4);
  int* fillpos = (int*)carve((size_t)N * 4);
  int* row_ptr = (int*)carve((size_t)(N + 1) * 4);
  int* col     = (int*)carve((size_t)ET * 4);
  f16* xh      = (f16*)carve((size_t)N * 32 * 2);
  f16* h0      = (f16*)carve((size_t)N * 128 * 2);
  f16* WT      = (f16*)carve((size_t)2048 * 2048 * 2);
  f16* Hb      = (f16*)carve((size_t)N * 2048 * 2);   // fp16 h for layers 1,2
  float* H3    = (float*)carve((size_t)N * 512 * 4);  // fp32 h for layer 3
  f16* XB      = (f16*)carve((size_t)N * 2048 * 2);
  float* asrc  = (float*)carve((size_t)N * 8 * 4);
  float* adst  = (float*)carve((size_t)N * 8 * 4);
  float* alpha = (float*)carve((size_t)ET * 8 * 4);

  if (off > ws_size) return;

  const int MT = (N + 127) / 128;   // 79 row-tiles
  float* out = (float*)d_out;

  // CSR build
  detect_kernel<<<1, 1, 0, stream>>>(ei, flag);
  init_kernel<<<(N + 255) / 256, 256, 0, stream>>>(cnt, fillpos, N);
  count_edges<<<(E + 255) / 256, 256, 0, stream>>>(ei, E, flag, cnt);
  scan_kernel<<<1, SCAN_T, 0, stream>>>(cnt, row_ptr, N);
  selfloop_kernel<<<(N + 255) / 256, 256, 0, stream>>>(row_ptr, col, N);
  fill_edges<<<(E + 255) / 256, 256, 0, stream>>>(ei, E, flag, row_ptr, fillpos, col);

  // input projection: h0 = lrelu(x @ W_in + b_in) -> fp16
  convert_f16<<<((long)N * 32 + 255) / 256, 256, 0, stream>>>(x, xh, (long)N * 32);
  convert_wT<<<dim3(1, 4), dim3(32, 8), 0, stream>>>(W_in, WT, 32, 128);
  gemm_kernel<1, 4, false><<<MT * 1, 256, 0, stream>>>(xh, WT, nullptr, h0, b_in,
      nullptr, nullptr, nullptr, nullptr, 0, 0, N, 128, 32, MT, 1);

  // ---- GAT layer 1: 128 -> 8x256 ----
  convert_wT<<<dim3(4, 64), dim3(32, 8), 0, stream>>>(W1, WT, 128, 2048);
  hipMemsetAsync(asrc, 0, (size_t)N * 8 * 4, stream);
  hipMemsetAsync(adst, 0, (size_t)N * 8 * 4, stream);
  gemm_kernel<2, 4, true><<<MT * 16, 256, 0, stream>>>(h0, WT, nullptr, Hb, nullptr,
      as1, ad1, asrc, adst, 8, 256, N, 2048, 128, MT, 16);
  softmax_kernel<8><<<(N + 3) / 4, 256, 0, stream>>>(row_ptr, col, asrc, adst, alpha, N);
  agg_kernel<2048, 256, false, true><<<N, 256, 0, stream>>>(Hb, alpha, row_ptr, col, b1,
      XB, nullptr);

  // ---- GAT layer 2: 2048 -> 8x256 ----
  convert_wT<<<dim3(64, 64), dim3(32, 8), 0, stream>>>(W2, WT, 2048, 2048);
  hipMemsetAsync(asrc, 0, (size_t)N * 8 * 4, stream);
  hipMemsetAsync(adst, 0, (size_t)N * 8 * 4, stream);
  gemm_kernel<2, 4, true><<<MT * 16, 256, 0, stream>>>(XB, WT, nullptr, Hb, nullptr,
      as2, ad2, asrc, adst, 8, 256, N, 2048, 2048, MT, 16);
  softmax_kernel<8><<<(N + 3) / 4, 256, 0, stream>>>(row_ptr, col, asrc, adst, alpha, N);
  agg_kernel<2048, 256, false, true><<<N, 256, 0, stream>>>(Hb, alpha, row_ptr, col, b2,
      XB, nullptr);

  // ---- GAT layer 3: 2048 -> 1x512 (fp32 h, BN=64 for occupancy) ----
  convert_wT<<<dim3(64, 16), dim3(32, 8), 0, stream>>>(W3, WT, 2048, 512);
  hipMemsetAsync(asrc, 0, (size_t)N * 4, stream);
  hipMemsetAsync(adst, 0, (size_t)N * 4, stream);
  gemm_kernel<0, 2, true><<<MT * 8, 256, 0, stream>>>(XB, WT, H3, nullptr, nullptr,
      as3, ad3, asrc, adst, 1, 512, N, 512, 2048, MT, 8);
  softmax_kernel<1><<<(N + 3) / 4, 256, 0, stream>>>(row_ptr, col, asrc, adst, alpha, N);
  agg_kernel<512, 512, true, false><<<N, 256, 0, stream>>>(H3, alpha, row_ptr, col, b3,
      nullptr, out);
}

// Round 5
// 467.312 us; speedup vs baseline: 1.0139x; 1.0139x over previous
//
#include <hip/hip_runtime.h>

typedef unsigned short u16;
typedef unsigned int u32;
typedef _Float16 f16;
typedef f16 f16x8 __attribute__((ext_vector_type(8)));
typedef float f32x4 __attribute__((ext_vector_type(4)));

__device__ __forceinline__ float h2f(f16 h){ return (float)h; }
__device__ __forceinline__ f16 f2h(float f){ return (f16)f; }

__device__ __forceinline__ f16x8 ldfrag(const f16* p){
  union { uint4 u; f16x8 h; } x;
  x.u = *(const uint4*)p;
  return x.h;
}
__device__ __forceinline__ void gload_lds16(const f16* g, f16* l){
  __builtin_amdgcn_global_load_lds(
      (const __attribute__((address_space(1))) u32*)g,
      (__attribute__((address_space(3))) u32*)l, 16, 0, 0);
}

// ---------------- CSR build ----------------

__global__ void detect_kernel(const int* __restrict__ ei, int* __restrict__ flag){
  if (threadIdx.x == 0 && blockIdx.x == 0){
    int orv = 0;
    for (int i = 0; i < 200; i++) orv |= ei[2*i + 1];
    *flag = (orv == 0) ? 1 : 0;
  }
}

__global__ void init_kernel(int* __restrict__ cnt, int* __restrict__ fillpos, int n){
  int i = blockIdx.x * blockDim.x + threadIdx.x;
  if (i < n){ cnt[i] = 1; fillpos[i] = 1; } // slot 0 = self loop
}

__global__ void count_edges(const int* __restrict__ ei, int E, const int* __restrict__ flag,
                            int* __restrict__ cnt){
  int e = blockIdx.x * blockDim.x + threadIdx.x;
  if (e >= E) return;
  int dst = (*flag) ? ei[2*E + 2*e] : ei[E + e];
  atomicAdd(&cnt[dst], 1);
}

#define SCAN_T 1024
__global__ void scan_kernel(const int* __restrict__ cnt, int* __restrict__ row_ptr, int n){
  __shared__ int sm[SCAN_T];
  int t = threadIdx.x;
  int chunk = (n + SCAN_T - 1) / SCAN_T;
  int lo = t * chunk, hi = lo + chunk; if (hi > n) hi = n; if (lo > n) lo = n;
  int s = 0;
  for (int i = lo; i < hi; i++) s += cnt[i];
  sm[t] = s; __syncthreads();
  for (int off = 1; off < SCAN_T; off <<= 1){
    int v = (t >= off) ? sm[t - off] : 0;
    __syncthreads();
    sm[t] += v;
    __syncthreads();
  }
  int base = sm[t] - s;
  for (int i = lo; i < hi; i++){ row_ptr[i] = base; base += cnt[i]; }
  if (t == 0) row_ptr[n] = sm[SCAN_T - 1];
}

__global__ void selfloop_kernel(const int* __restrict__ row_ptr, int* __restrict__ col, int n){
  int i = blockIdx.x * blockDim.x + threadIdx.x;
  if (i < n) col[row_ptr[i]] = i;
}

__global__ void fill_edges(const int* __restrict__ ei, int E, const int* __restrict__ flag,
                           const int* __restrict__ row_ptr, int* __restrict__ fillpos,
                           int* __restrict__ col){
  int e = blockIdx.x * blockDim.x + threadIdx.x;
  if (e >= E) return;
  int f = *flag;
  int src = f ? ei[2*e]       : ei[e];
  int dst = f ? ei[2*E + 2*e] : ei[E + e];
  int off = atomicAdd(&fillpos[dst], 1);
  col[row_ptr[dst] + off] = src;
}

// ---------------- converts ----------------

__global__ void convert_f16(const float* __restrict__ X, f16* __restrict__ Xo, long n){
  long i = blockIdx.x * (long)blockDim.x + threadIdx.x;
  if (i >= n) return;
  Xo[i] = f2h(X[i]);
}

// W [K][N] fp32 -> WT [N][K] fp16 (tiled transpose)
__global__ void convert_wT(const float* __restrict__ W, f16* __restrict__ T, int K, int N){
  __shared__ float sm[32][33];
  int kb = blockIdx.x * 32, nb = blockIdx.y * 32;
  int tx = threadIdx.x, ty = threadIdx.y; // (32,8)
  for (int i = 0; i < 32; i += 8)
    sm[ty + i][tx] = W[(size_t)(kb + ty + i) * N + nb + tx];
  __syncthreads();
  for (int i = 0; i < 32; i += 8)
    T[(size_t)(nb + ty + i) * K + kb + tx] = f2h(sm[tx][ty + i]);
}

// ---------------- fp16 MFMA GEMM (single-buffer m97-style loop) ----------------
// C[M][N] = A[M][K] @ B[K][N]; A row-major fp16, B as WT[N][K] fp16.
// Tile 128 x (FJ*32); 4 waves 2x2; wave = 64 rows x FJ*16 cols; BK=32.
// EPI 0: fp32 C.  EPI 1: bias+lrelu -> fp16.  EPI 2: plain fp16.
// FA: fused alpha_src/dst = rowwise dot with flat a_s[n]/a_d[n], atomicAdd.

template<int EPI, int FJ, bool FA>
__global__ __launch_bounds__(256) void gemm_kernel(
    const f16* __restrict__ A, const f16* __restrict__ B,
    float* __restrict__ C, f16* __restrict__ Ch,
    const float* __restrict__ bias,
    const float* __restrict__ asf, const float* __restrict__ adf,
    float* __restrict__ asrc, float* __restrict__ adst, int HEADS, int CH,
    int M, int N, int K, int nbm, int nbn)
{
  constexpr int BN = FJ * 32;
  __shared__ f16 sA[128 * 32];
  __shared__ f16 sB[BN * 32];

  // bijective XCD swizzle (m204)
  int nwg = nbm * nbn;
  int bid = blockIdx.x;
  int q = nwg >> 3, r = nwg & 7;
  int xcd = bid & 7, idx = bid >> 3;
  int wg = (xcd < r ? xcd * (q + 1) : r * (q + 1) + (xcd - r) * q) + idx;
  int bm = wg / nbn, bn = wg % nbn;

  int tid = threadIdx.x;
  int lane = tid & 63;
  int w = tid >> 6;
  int wr = (w >> 1) * 64, wc = (w & 1) * (FJ * 16);
  int lm = lane & 15, lk = (lane >> 4) * 8;

  int sk = (tid & 3) * 8;
  long ar0 = (long)bm * 128 + (tid >> 2);
  long ar1 = ar0 + 64;
  if (ar0 >= M) ar0 = M - 1;   // clamped rows only feed unstored outputs
  if (ar1 >= M) ar1 = M - 1;
  long br0 = (long)bn * BN + (tid >> 2);  // N multiple of BN
  long br1 = br0 + 64;                    // used only when FJ==4

  const f16* pA0 = A + ar0 * K + sk;
  const f16* pA1 = A + ar1 * K + sk;
  const f16* pB0 = B + br0 * K + sk;
  const f16* pB1 = (FJ == 4) ? (B + br1 * K + sk) : pB0;
  const int d1 = 2048;  // 64 rows * 32 elems

  f32x4 acc[4][FJ] = {};

  for (int k0 = 0; k0 < K; k0 += 32){
    gload_lds16(pA0 + k0, &sA[tid * 8]);
    gload_lds16(pA1 + k0, &sA[d1 + tid * 8]);
    gload_lds16(pB0 + k0, &sB[tid * 8]);
    if constexpr (FJ == 4)
      gload_lds16(pB1 + k0, &sB[d1 + tid * 8]);
    __syncthreads();   // drains vmcnt before barrier

    f16x8 af[4], bfr[FJ];
    #pragma unroll
    for (int f = 0; f < 4; f++)
      af[f] = ldfrag(&sA[(wr + f * 16 + lm) * 32 + lk]);
    #pragma unroll
    for (int f = 0; f < FJ; f++)
      bfr[f] = ldfrag(&sB[(wc + f * 16 + lm) * 32 + lk]);
    #pragma unroll
    for (int fi = 0; fi < 4; fi++)
      #pragma unroll
      for (int fj = 0; fj < FJ; fj++)
        acc[fi][fj] = __builtin_amdgcn_mfma_f32_16x16x32_f16(af[fi], bfr[fj], acc[fi][fj], 0, 0, 0);
    __syncthreads();
  }

  // ---- store epilogue ----
  #pragma unroll
  for (int fi = 0; fi < 4; fi++){
    int mb = bm * 128 + wr + fi * 16 + ((lane >> 4) << 2);
    #pragma unroll
    for (int fj = 0; fj < FJ; fj++){
      int n = bn * BN + wc + fj * 16 + lm;
      #pragma unroll
      for (int j = 0; j < 4; j++){
        int m = mb + j;
        if (m < M){
          float v = acc[fi][fj][j];
          size_t o = (size_t)m * N + n;
          if (EPI == 0){
            C[o] = v;
          } else if (EPI == 2){
            Ch[o] = f2h(v);
          } else {
            v += bias[n];
            v = v > 0.0f ? v : 0.2f * v;
            Ch[o] = f2h(v);
          }
        }
      }
    }
  }

  // ---- fused alpha epilogue ----
  if constexpr (FA){
    int hd = (bn * BN) / CH;      // block lies within one head band
    #pragma unroll
    for (int fi = 0; fi < 4; fi++){
      int mb = bm * 128 + wr + fi * 16 + ((lane >> 4) << 2);
      #pragma unroll
      for (int j = 0; j < 4; j++){
        float pa = 0.0f, pd = 0.0f;
        #pragma unroll
        for (int fj = 0; fj < FJ; fj++){
          int n = bn * BN + wc + fj * 16 + lm;
          float v = acc[fi][fj][j];
          pa += v * asf[n];
          pd += v * adf[n];
        }
        #pragma unroll
        for (int mk = 1; mk < 16; mk <<= 1){
          pa += __shfl_xor(pa, mk);
          pd += __shfl_xor(pd, mk);
        }
        int m = mb + j;
        if ((lane & 15) == 0 && m < M){
          atomicAdd(&asrc[m * HEADS + hd], pa);
          atomicAdd(&adst[m * HEADS + hd], pd);
        }
      }
    }
  }
}

// ---------------- fused segment-softmax + aggregation ----------------
// Block per dst node. Phase A: wave 0 computes per-head max & 1/sum.
// Phase B: all 256 threads recompute edge weights and aggregate features.

template<int HEADS, int CH, bool FINAL>
__global__ __launch_bounds__(256) void smax_agg_kernel(
    const f16* __restrict__ H, const int* __restrict__ row_ptr,
    const int* __restrict__ col,
    const float* __restrict__ asrc, const float* __restrict__ adst,
    const float* __restrict__ bias, f16* __restrict__ Oh, float* __restrict__ Ofp)
{
  constexpr int F = HEADS * CH;
  constexpr int CPT = F / 256;
  __shared__ float s_m[HEADS], s_inv[HEADS];
  int dst = blockIdx.x;
  int t = threadIdx.x;
  int s = row_ptr[dst], e = row_ptr[dst + 1];

  if (t < 64){
    const int hd = (HEADS == 8) ? (t & 7) : 0;
    const int el = (HEADS == 8) ? (t >> 3) : t;
    const int EPP = 64 / HEADS;
    float ad = adst[dst * HEADS + hd];
    float m = -1e30f;
    for (int p = s + el; p < e; p += EPP){
      float v = asrc[col[p] * HEADS + hd] + ad;
      v = v > 0.0f ? v : 0.2f * v;
      m = fmaxf(m, v);
    }
    for (int off = HEADS; off < 64; off <<= 1) m = fmaxf(m, __shfl_xor(m, off));
    float sum = 0.0f;
    for (int p = s + el; p < e; p += EPP){
      float v = asrc[col[p] * HEADS + hd] + ad;
      v = v > 0.0f ? v : 0.2f * v;
      sum += __expf(v - m);
    }
    for (int off = HEADS; off < 64; off <<= 1) sum += __shfl_xor(sum, off);
    if (el == 0){ s_m[hd] = m; s_inv[hd] = 1.0f / (sum + 1e-16f); }
  }
  __syncthreads();

  int c0 = t * CPT;
  int hd = c0 / CH;
  float m = s_m[hd], inv = s_inv[hd];
  float ad = adst[dst * HEADS + hd];
  float acc[CPT] = {};
  int p = s;

  auto wgt = [&](int src) -> float {
    float v = asrc[src * HEADS + hd] + ad;
    v = v > 0.0f ? v : 0.2f * v;
    return __expf(v - m) * inv;
  };

  for (; p + 4 <= e; p += 4){
    int i0 = col[p], i1 = col[p+1], i2 = col[p+2], i3 = col[p+3];
    if (CPT == 8){
      union { uint4 u; f16 h[8]; } x0, x1, x2, x3;
      x0.u = *(const uint4*)(H + (size_t)i0 * F + c0);
      x1.u = *(const uint4*)(H + (size_t)i1 * F + c0);
      x2.u = *(const uint4*)(H + (size_t)i2 * F + c0);
      x3.u = *(const uint4*)(H + (size_t)i3 * F + c0);
      float w0 = wgt(i0), w1 = wgt(i1), w2 = wgt(i2), w3 = wgt(i3);
      #pragma unroll
      for (int i = 0; i < 8; i++)
        acc[i] += w0 * h2f(x0.h[i]) + w1 * h2f(x1.h[i])
                + w2 * h2f(x2.h[i]) + w3 * h2f(x3.h[i]);
    } else {
      union { u32 u; f16 h[2]; } x0, x1, x2, x3;
      x0.u = *(const u32*)(H + (size_t)i0 * F + c0);
      x1.u = *(const u32*)(H + (size_t)i1 * F + c0);
      x2.u = *(const u32*)(H + (size_t)i2 * F + c0);
      x3.u = *(const u32*)(H + (size_t)i3 * F + c0);
      float w0 = wgt(i0), w1 = wgt(i1), w2 = wgt(i2), w3 = wgt(i3);
      acc[0] += w0 * h2f(x0.h[0]) + w1 * h2f(x1.h[0]) + w2 * h2f(x2.h[0]) + w3 * h2f(x3.h[0]);
      acc[1] += w0 * h2f(x0.h[1]) + w1 * h2f(x1.h[1]) + w2 * h2f(x2.h[1]) + w3 * h2f(x3.h[1]);
    }
  }
  for (; p < e; p++){
    int src = col[p];
    float w0 = wgt(src);
    if (CPT == 8){
      union { uint4 u; f16 h[8]; } x;
      x.u = *(const uint4*)(H + (size_t)src * F + c0);
      #pragma unroll
      for (int i = 0; i < 8; i++) acc[i] += w0 * h2f(x.h[i]);
    } else {
      union { u32 u; f16 h[2]; } x;
      x.u = *(const u32*)(H + (size_t)src * F + c0);
      acc[0] += w0 * h2f(x.h[0]); acc[1] += w0 * h2f(x.h[1]);
    }
  }

  #pragma unroll
  for (int i = 0; i < CPT; i++){
    float v = acc[i] + bias[c0 + i];
    v = v > 0.0f ? v : 0.2f * v;
    size_t o = (size_t)dst * F + c0 + i;
    if (FINAL) Ofp[o] = v;
    else       Oh[o]  = f2h(v);
  }
}

// ---------------- launcher ----------------

extern "C" void kernel_launch(void* const* d_in, const int* in_sizes, int n_in,
                              void* d_out, int out_size, void* d_ws, size_t ws_size,
                              hipStream_t stream)
{
  const float* x    = (const float*)d_in[0];
  const int*   ei   = (const int*)d_in[1];
  const float* W_in = (const float*)d_in[2];
  const float* b_in = (const float*)d_in[3];
  const float* W1   = (const float*)d_in[4];
  const float* as1  = (const float*)d_in[5];
  const float* ad1  = (const float*)d_in[6];
  const float* b1   = (const float*)d_in[7];
  const float* W2   = (const float*)d_in[8];
  const float* as2  = (const float*)d_in[9];
  const float* ad2  = (const float*)d_in[10];
  const float* b2   = (const float*)d_in[11];
  const float* W3   = (const float*)d_in[12];
  const float* as3  = (const float*)d_in[13];
  const float* ad3  = (const float*)d_in[14];
  const float* b3   = (const float*)d_in[15];

  const int N  = in_sizes[0] / 32;   // 10000
  const int E  = in_sizes[1] / 2;    // 80000
  const int ET = E + N;

  char* w = (char*)d_ws;
  size_t off = 0;
  auto carve = [&](size_t bytes) -> char* {
    off = (off + 255) & ~(size_t)255;
    char* p = w + off;
    off += bytes;
    return p;
  };

  int* flag    = (int*)carve(4);
  int* cnt     = (int*)carve((size_t)N * 4);
  int* fillpos = (int*)carve((size_t)N * 4);
  int* row_ptr = (int*)carve((size_t)(N + 1) * 4);
  int* col     = (int*)carve((size_t)ET * 4);
  f16* xh      = (f16*)carve((size_t)N * 32 * 2);
  f16* h0      = (f16*)carve((size_t)N * 128 * 2);
  f16* WT      = (f16*)carve((size_t)2048 * 2048 * 2);
  f16* Hb      = (f16*)carve((size_t)N * 2048 * 2);   // fp16 h for layers 1,2
  f16* H3      = (f16*)carve((size_t)N * 512 * 2);    // fp16 h for layer 3
  f16* XB      = (f16*)carve((size_t)N * 2048 * 2);
  float* asrc  = (float*)carve((size_t)N * 8 * 4);
  float* adst  = (float*)carve((size_t)N * 8 * 4);

  if (off > ws_size) return;

  const int MT = (N + 127) / 128;   // 79 row-tiles
  float* out = (float*)d_out;

  // CSR build
  detect_kernel<<<1, 1, 0, stream>>>(ei, flag);
  init_kernel<<<(N + 255) / 256, 256, 0, stream>>>(cnt, fillpos, N);
  count_edges<<<(E + 255) / 256, 256, 0, stream>>>(ei, E, flag, cnt);
  scan_kernel<<<1, SCAN_T, 0, stream>>>(cnt, row_ptr, N);
  selfloop_kernel<<<(N + 255) / 256, 256, 0, stream>>>(row_ptr, col, N);
  fill_edges<<<(E + 255) / 256, 256, 0, stream>>>(ei, E, flag, row_ptr, fillpos, col);

  // input projection: h0 = lrelu(x @ W_in + b_in) -> fp16
  convert_f16<<<((long)N * 32 + 255) / 256, 256, 0, stream>>>(x, xh, (long)N * 32);
  convert_wT<<<dim3(1, 4), dim3(32, 8), 0, stream>>>(W_in, WT, 32, 128);
  gemm_kernel<1, 4, false><<<MT * 1, 256, 0, stream>>>(xh, WT, nullptr, h0, b_in,
      nullptr, nullptr, nullptr, nullptr, 0, 0, N, 128, 32, MT, 1);

  // ---- GAT layer 1: 128 -> 8x256 ----
  convert_wT<<<dim3(4, 64), dim3(32, 8), 0, stream>>>(W1, WT, 128, 2048);
  hipMemsetAsync(asrc, 0, (size_t)N * 8 * 4, stream);
  hipMemsetAsync(adst, 0, (size_t)N * 8 * 4, stream);
  gemm_kernel<2, 4, true><<<MT * 16, 256, 0, stream>>>(h0, WT, nullptr, Hb, nullptr,
      as1, ad1, asrc, adst, 8, 256, N, 2048, 128, MT, 16);
  smax_agg_kernel<8, 256, false><<<N, 256, 0, stream>>>(Hb, row_ptr, col,
      asrc, adst, b1, XB, nullptr);

  // ---- GAT layer 2: 2048 -> 8x256 ----
  convert_wT<<<dim3(64, 64), dim3(32, 8), 0, stream>>>(W2, WT, 2048, 2048);
  hipMemsetAsync(asrc, 0, (size_t)N * 8 * 4, stream);
  hipMemsetAsync(adst, 0, (size_t)N * 8 * 4, stream);
  gemm_kernel<2, 4, true><<<MT * 16, 256, 0, stream>>>(XB, WT, nullptr, Hb, nullptr,
      as2, ad2, asrc, adst, 8, 256, N, 2048, 2048, MT, 16);
  smax_agg_kernel<8, 256, false><<<N, 256, 0, stream>>>(Hb, row_ptr, col,
      asrc, adst, b2, XB, nullptr);

  // ---- GAT layer 3: 2048 -> 1x512 ----
  convert_wT<<<dim3(64, 16), dim3(32, 8), 0, stream>>>(W3, WT, 2048, 512);
  hipMemsetAsync(asrc, 0, (size_t)N * 4, stream);
  hipMemsetAsync(adst, 0, (size_t)N * 4, stream);
  gemm_kernel<2, 2, true><<<MT * 8, 256, 0, stream>>>(XB, WT, nullptr, H3, nullptr,
      as3, ad3, asrc, adst, 1, 512, N, 512, 2048, MT, 8);
  smax_agg_kernel<1, 512, true><<<N, 256, 0, stream>>>(H3, row_ptr, col,
      asrc, adst, b3, nullptr, out);
}

// Round 6
// 392.039 us; speedup vs baseline: 1.2085x; 1.1920x over previous
//
#include <hip/hip_runtime.h>

typedef unsigned short u16;
typedef unsigned int u32;
typedef _Float16 f16;
typedef f16 f16x8 __attribute__((ext_vector_type(8)));
typedef float f32x4 __attribute__((ext_vector_type(4)));

__device__ __forceinline__ float h2f(f16 h){ return (float)h; }
__device__ __forceinline__ f16 f2h(float f){ return (f16)f; }

__device__ __forceinline__ f16x8 ldfrag(const f16* p){
  union { uint4 u; f16x8 h; } x;
  x.u = *(const uint4*)p;
  return x.h;
}
__device__ __forceinline__ void gload_lds16(const f16* g, f16* l){
  __builtin_amdgcn_global_load_lds(
      (const __attribute__((address_space(1))) u32*)g,
      (__attribute__((address_space(3))) u32*)l, 16, 0, 0);
}

// ---------------- CSR build ----------------

__global__ void detect_kernel(const int* __restrict__ ei, int* __restrict__ flag){
  if (threadIdx.x == 0 && blockIdx.x == 0){
    int orv = 0;
    for (int i = 0; i < 200; i++) orv |= ei[2*i + 1];
    *flag = (orv == 0) ? 1 : 0;
  }
}

__global__ void init_kernel(int* __restrict__ cnt, int* __restrict__ fillpos, int n){
  int i = blockIdx.x * blockDim.x + threadIdx.x;
  if (i < n){ cnt[i] = 1; fillpos[i] = 1; } // slot 0 = self loop
}

__global__ void count_edges(const int* __restrict__ ei, int E, const int* __restrict__ flag,
                            int* __restrict__ cnt){
  int e = blockIdx.x * blockDim.x + threadIdx.x;
  if (e >= E) return;
  int dst = (*flag) ? ei[2*E + 2*e] : ei[E + e];
  atomicAdd(&cnt[dst], 1);
}

#define SCAN_T 1024
__global__ void scan_kernel(const int* __restrict__ cnt, int* __restrict__ row_ptr, int n){
  __shared__ int sm[SCAN_T];
  int t = threadIdx.x;
  int chunk = (n + SCAN_T - 1) / SCAN_T;
  int lo = t * chunk, hi = lo + chunk; if (hi > n) hi = n; if (lo > n) lo = n;
  int s = 0;
  for (int i = lo; i < hi; i++) s += cnt[i];
  sm[t] = s; __syncthreads();
  for (int off = 1; off < SCAN_T; off <<= 1){
    int v = (t >= off) ? sm[t - off] : 0;
    __syncthreads();
    sm[t] += v;
    __syncthreads();
  }
  int base = sm[t] - s;
  for (int i = lo; i < hi; i++){ row_ptr[i] = base; base += cnt[i]; }
  if (t == 0) row_ptr[n] = sm[SCAN_T - 1];
}

__global__ void selfloop_kernel(const int* __restrict__ row_ptr, int* __restrict__ col, int n){
  int i = blockIdx.x * blockDim.x + threadIdx.x;
  if (i < n) col[row_ptr[i]] = i;
}

__global__ void fill_edges(const int* __restrict__ ei, int E, const int* __restrict__ flag,
                           const int* __restrict__ row_ptr, int* __restrict__ fillpos,
                           int* __restrict__ col){
  int e = blockIdx.x * blockDim.x + threadIdx.x;
  if (e >= E) return;
  int f = *flag;
  int src = f ? ei[2*e]       : ei[e];
  int dst = f ? ei[2*E + 2*e] : ei[E + e];
  int off = atomicAdd(&fillpos[dst], 1);
  col[row_ptr[dst] + off] = src;
}

// ---------------- converts ----------------

__global__ void convert_f16(const float* __restrict__ X, f16* __restrict__ Xo, long n){
  long i = blockIdx.x * (long)blockDim.x + threadIdx.x;
  if (i >= n) return;
  Xo[i] = f2h(X[i]);
}

// W [K][N] fp32 -> WT [N][K] fp16 (tiled transpose)
__global__ void convert_wT(const float* __restrict__ W, f16* __restrict__ T, int K, int N){
  __shared__ float sm[32][33];
  int kb = blockIdx.x * 32, nb = blockIdx.y * 32;
  int tx = threadIdx.x, ty = threadIdx.y; // (32,8)
  for (int i = 0; i < 32; i += 8)
    sm[ty + i][tx] = W[(size_t)(kb + ty + i) * N + nb + tx];
  __syncthreads();
  for (int i = 0; i < 32; i += 8)
    T[(size_t)(nb + ty + i) * K + kb + tx] = f2h(sm[tx][ty + i]);
}

// ---------------- fp16 MFMA GEMM, 2-phase double-buffered ----------------
// C[M][N] = A[M][K] @ B[K][N]; A row-major fp16, B as WT[N][K] fp16.
// Tile 128 x (FJ*32); 4 waves 2x2; wave = 64 rows x FJ*16 cols; BK=32.
// Double-buffered LDS: next tile's global_load_lds issued before compute,
// single barrier per K-step (dbuf beat single-buf 166 vs 180 in R4/R5 A/B).
// EPI 0: fp32 C.  EPI 1: bias+lrelu -> fp16.  EPI 2: plain fp16.

template<int EPI, int FJ>
__global__ __launch_bounds__(256) void gemm_kernel(
    const f16* __restrict__ A, const f16* __restrict__ B,
    float* __restrict__ C, f16* __restrict__ Ch,
    const float* __restrict__ bias,
    int M, int N, int K, int nbm, int nbn)
{
  constexpr int BN = FJ * 32;
  __shared__ f16 sA[2][128 * 32];
  __shared__ f16 sB[2][BN * 32];

  // bijective XCD swizzle (m204)
  int nwg = nbm * nbn;
  int bid = blockIdx.x;
  int q = nwg >> 3, r = nwg & 7;
  int xcd = bid & 7, idx = bid >> 3;
  int wg = (xcd < r ? xcd * (q + 1) : r * (q + 1) + (xcd - r) * q) + idx;
  int bm = wg / nbn, bn = wg % nbn;

  int tid = threadIdx.x;
  int lane = tid & 63;
  int w = tid >> 6;
  int wr = (w >> 1) * 64, wc = (w & 1) * (FJ * 16);
  int lm = lane & 15, lk = (lane >> 4) * 8;

  int sk = (tid & 3) * 8;
  long ar0 = (long)bm * 128 + (tid >> 2);
  long ar1 = ar0 + 64;
  if (ar0 >= M) ar0 = M - 1;   // clamped rows only feed unstored outputs
  if (ar1 >= M) ar1 = M - 1;
  long br0 = (long)bn * BN + (tid >> 2);  // N multiple of BN
  long br1 = br0 + 64;                    // used only when FJ==4

  const f16* pA0 = A + ar0 * K + sk;
  const f16* pA1 = A + ar1 * K + sk;
  const f16* pB0 = B + br0 * K + sk;
  const f16* pB1 = (FJ == 4) ? (B + br1 * K + sk) : pB0;
  const int d1 = 2048;  // 64 rows * 32 elems

  auto STAGE = [&](int buf, int k0){
    gload_lds16(pA0 + k0, &sA[buf][tid * 8]);
    gload_lds16(pA1 + k0, &sA[buf][d1 + tid * 8]);
    gload_lds16(pB0 + k0, &sB[buf][tid * 8]);
    if constexpr (FJ == 4)
      gload_lds16(pB1 + k0, &sB[buf][d1 + tid * 8]);
  };

  f32x4 acc[4][FJ] = {};

  int nt = K >> 5;
  STAGE(0, 0);
  __syncthreads();          // vmcnt(0) drain + barrier: buf0 ready
  int cur = 0;
  for (int t = 0; t < nt; t++){
    if (t + 1 < nt) STAGE(cur ^ 1, (t + 1) * 32);   // overlap with compute
    f16x8 af[4], bfr[FJ];
    #pragma unroll
    for (int f = 0; f < 4; f++)
      af[f] = ldfrag(&sA[cur][(wr + f * 16 + lm) * 32 + lk]);
    #pragma unroll
    for (int f = 0; f < FJ; f++)
      bfr[f] = ldfrag(&sB[cur][(wc + f * 16 + lm) * 32 + lk]);
    #pragma unroll
    for (int fi = 0; fi < 4; fi++)
      #pragma unroll
      for (int fj = 0; fj < FJ; fj++)
        acc[fi][fj] = __builtin_amdgcn_mfma_f32_16x16x32_f16(af[fi], bfr[fj], acc[fi][fj], 0, 0, 0);
    __syncthreads();        // drains next-tile loads; all waves done with cur
    cur ^= 1;
  }

  // ---- store epilogue ----
  #pragma unroll
  for (int fi = 0; fi < 4; fi++){
    int mb = bm * 128 + wr + fi * 16 + ((lane >> 4) << 2);
    #pragma unroll
    for (int fj = 0; fj < FJ; fj++){
      int n = bn * BN + wc + fj * 16 + lm;
      #pragma unroll
      for (int j = 0; j < 4; j++){
        int m = mb + j;
        if (m < M){
          float v = acc[fi][fj][j];
          size_t o = (size_t)m * N + n;
          if (EPI == 0){
            C[o] = v;
          } else if (EPI == 2){
            Ch[o] = f2h(v);
          } else {
            v += bias[n];
            v = v > 0.0f ? v : 0.2f * v;
            Ch[o] = f2h(v);
          }
        }
      }
    }
  }
}

// ---------------- attention coefficients (fp16 H) ----------------

template<int HEADS, int CH>
__global__ __launch_bounds__(256) void alpha_kernel(
    const f16* __restrict__ H, const float* __restrict__ a_s, const float* __restrict__ a_d,
    float* __restrict__ asrc, float* __restrict__ adst, int Nn)
{
  int gw = blockIdx.x * 4 + (threadIdx.x >> 6);
  int lane = threadIdx.x & 63;
  int node = gw / HEADS, hd = gw % HEADS;
  if (node >= Nn) return;
  size_t base = (size_t)node * HEADS * CH + hd * CH;
  const float* asp = a_s + hd * CH;
  const float* adp = a_d + hd * CH;
  float s1 = 0.0f, s2 = 0.0f;
  #pragma unroll
  for (int i = 0; i < CH / 256; i++){
    int off = i * 256 + lane * 4;
    union { uint2 u; f16 h[4]; } x;
    x.u = *(const uint2*)(H + base + off);
    float4 s4 = *(const float4*)(asp + off);
    float4 d4 = *(const float4*)(adp + off);
    s1 += h2f(x.h[0]) * s4.x + h2f(x.h[1]) * s4.y + h2f(x.h[2]) * s4.z + h2f(x.h[3]) * s4.w;
    s2 += h2f(x.h[0]) * d4.x + h2f(x.h[1]) * d4.y + h2f(x.h[2]) * d4.z + h2f(x.h[3]) * d4.w;
  }
  for (int off = 32; off; off >>= 1){
    s1 += __shfl_xor(s1, off);
    s2 += __shfl_xor(s2, off);
  }
  if (lane == 0){ asrc[gw] = s1; adst[gw] = s2; }
}

// ---------------- fused segment-softmax + aggregation ----------------
// Block per dst node. Phase A: wave 0 computes per-head max & 1/sum.
// Phase B: all 256 threads recompute edge weights and aggregate features.

template<int HEADS, int CH, bool FINAL>
__global__ __launch_bounds__(256) void smax_agg_kernel(
    const f16* __restrict__ H, const int* __restrict__ row_ptr,
    const int* __restrict__ col,
    const float* __restrict__ asrc, const float* __restrict__ adst,
    const float* __restrict__ bias, f16* __restrict__ Oh, float* __restrict__ Ofp)
{
  constexpr int F = HEADS * CH;
  constexpr int CPT = F / 256;
  __shared__ float s_m[HEADS], s_inv[HEADS];
  int dst = blockIdx.x;
  int t = threadIdx.x;
  int s = row_ptr[dst], e = row_ptr[dst + 1];

  if (t < 64){
    const int hd = (HEADS == 8) ? (t & 7) : 0;
    const int el = (HEADS == 8) ? (t >> 3) : t;
    const int EPP = 64 / HEADS;
    float ad = adst[dst * HEADS + hd];
    float m = -1e30f;
    for (int p = s + el; p < e; p += EPP){
      float v = asrc[col[p] * HEADS + hd] + ad;
      v = v > 0.0f ? v : 0.2f * v;
      m = fmaxf(m, v);
    }
    for (int off = HEADS; off < 64; off <<= 1) m = fmaxf(m, __shfl_xor(m, off));
    float sum = 0.0f;
    for (int p = s + el; p < e; p += EPP){
      float v = asrc[col[p] * HEADS + hd] + ad;
      v = v > 0.0f ? v : 0.2f * v;
      sum += __expf(v - m);
    }
    for (int off = HEADS; off < 64; off <<= 1) sum += __shfl_xor(sum, off);
    if (el == 0){ s_m[hd] = m; s_inv[hd] = 1.0f / (sum + 1e-16f); }
  }
  __syncthreads();

  int c0 = t * CPT;
  int hd = c0 / CH;
  float m = s_m[hd], inv = s_inv[hd];
  float ad = adst[dst * HEADS + hd];
  float acc[CPT] = {};
  int p = s;

  auto wgt = [&](int src) -> float {
    float v = asrc[src * HEADS + hd] + ad;
    v = v > 0.0f ? v : 0.2f * v;
    return __expf(v - m) * inv;
  };

  for (; p + 4 <= e; p += 4){
    int i0 = col[p], i1 = col[p+1], i2 = col[p+2], i3 = col[p+3];
    if (CPT == 8){
      union { uint4 u; f16 h[8]; } x0, x1, x2, x3;
      x0.u = *(const uint4*)(H + (size_t)i0 * F + c0);
      x1.u = *(const uint4*)(H + (size_t)i1 * F + c0);
      x2.u = *(const uint4*)(H + (size_t)i2 * F + c0);
      x3.u = *(const uint4*)(H + (size_t)i3 * F + c0);
      float w0 = wgt(i0), w1 = wgt(i1), w2 = wgt(i2), w3 = wgt(i3);
      #pragma unroll
      for (int i = 0; i < 8; i++)
        acc[i] += w0 * h2f(x0.h[i]) + w1 * h2f(x1.h[i])
                + w2 * h2f(x2.h[i]) + w3 * h2f(x3.h[i]);
    } else {
      union { u32 u; f16 h[2]; } x0, x1, x2, x3;
      x0.u = *(const u32*)(H + (size_t)i0 * F + c0);
      x1.u = *(const u32*)(H + (size_t)i1 * F + c0);
      x2.u = *(const u32*)(H + (size_t)i2 * F + c0);
      x3.u = *(const u32*)(H + (size_t)i3 * F + c0);
      float w0 = wgt(i0), w1 = wgt(i1), w2 = wgt(i2), w3 = wgt(i3);
      acc[0] += w0 * h2f(x0.h[0]) + w1 * h2f(x1.h[0]) + w2 * h2f(x2.h[0]) + w3 * h2f(x3.h[0]);
      acc[1] += w0 * h2f(x0.h[1]) + w1 * h2f(x1.h[1]) + w2 * h2f(x2.h[1]) + w3 * h2f(x3.h[1]);
    }
  }
  for (; p < e; p++){
    int src = col[p];
    float w0 = wgt(src);
    if (CPT == 8){
      union { uint4 u; f16 h[8]; } x;
      x.u = *(const uint4*)(H + (size_t)src * F + c0);
      #pragma unroll
      for (int i = 0; i < 8; i++) acc[i] += w0 * h2f(x.h[i]);
    } else {
      union { u32 u; f16 h[2]; } x;
      x.u = *(const u32*)(H + (size_t)src * F + c0);
      acc[0] += w0 * h2f(x.h[0]); acc[1] += w0 * h2f(x.h[1]);
    }
  }

  #pragma unroll
  for (int i = 0; i < CPT; i++){
    float v = acc[i] + bias[c0 + i];
    v = v > 0.0f ? v : 0.2f * v;
    size_t o = (size_t)dst * F + c0 + i;
    if (FINAL) Ofp[o] = v;
    else       Oh[o]  = f2h(v);
  }
}

// ---------------- launcher ----------------

extern "C" void kernel_launch(void* const* d_in, const int* in_sizes, int n_in,
                              void* d_out, int out_size, void* d_ws, size_t ws_size,
                              hipStream_t stream)
{
  const float* x    = (const float*)d_in[0];
  const int*   ei   = (const int*)d_in[1];
  const float* W_in = (const float*)d_in[2];
  const float* b_in = (const float*)d_in[3];
  const float* W1   = (const float*)d_in[4];
  const float* as1  = (const float*)d_in[5];
  const float* ad1  = (const float*)d_in[6];
  const float* b1   = (const float*)d_in[7];
  const float* W2   = (const float*)d_in[8];
  const float* as2  = (const float*)d_in[9];
  const float* ad2  = (const float*)d_in[10];
  const float* b2   = (const float*)d_in[11];
  const float* W3   = (const float*)d_in[12];
  const float* as3  = (const float*)d_in[13];
  const float* ad3  = (const float*)d_in[14];
  const float* b3   = (const float*)d_in[15];

  const int N  = in_sizes[0] / 32;   // 10000
  const int E  = in_sizes[1] / 2;    // 80000
  const int ET = E + N;

  char* w = (char*)d_ws;
  size_t off = 0;
  auto carve = [&](size_t bytes) -> char* {
    off = (off + 255) & ~(size_t)255;
    char* p = w + off;
    off += bytes;
    return p;
  };

  int* flag    = (int*)carve(4);
  int* cnt     = (int*)carve((size_t)N * 4);
  int* fillpos = (int*)carve((size_t)N * 4);
  int* row_ptr = (int*)carve((size_t)(N + 1) * 4);
  int* col     = (int*)carve((size_t)ET * 4);
  f16* xh      = (f16*)carve((size_t)N * 32 * 2);
  f16* h0      = (f16*)carve((size_t)N * 128 * 2);
  f16* WT      = (f16*)carve((size_t)2048 * 2048 * 2);
  f16* Hb      = (f16*)carve((size_t)N * 2048 * 2);   // fp16 h for layers 1,2
  f16* H3      = (f16*)carve((size_t)N * 512 * 2);    // fp16 h for layer 3
  f16* XB      = (f16*)carve((size_t)N * 2048 * 2);
  float* asrc  = (float*)carve((size_t)N * 8 * 4);
  float* adst  = (float*)carve((size_t)N * 8 * 4);

  if (off > ws_size) return;

  const int MT = (N + 127) / 128;   // 79 row-tiles
  float* out = (float*)d_out;

  // CSR build
  detect_kernel<<<1, 1, 0, stream>>>(ei, flag);
  init_kernel<<<(N + 255) / 256, 256, 0, stream>>>(cnt, fillpos, N);
  count_edges<<<(E + 255) / 256, 256, 0, stream>>>(ei, E, flag, cnt);
  scan_kernel<<<1, SCAN_T, 0, stream>>>(cnt, row_ptr, N);
  selfloop_kernel<<<(N + 255) / 256, 256, 0, stream>>>(row_ptr, col, N);
  fill_edges<<<(E + 255) / 256, 256, 0, stream>>>(ei, E, flag, row_ptr, fillpos, col);

  // input projection: h0 = lrelu(x @ W_in + b_in) -> fp16
  convert_f16<<<((long)N * 32 + 255) / 256, 256, 0, stream>>>(x, xh, (long)N * 32);
  convert_wT<<<dim3(1, 4), dim3(32, 8), 0, stream>>>(W_in, WT, 32, 128);
  gemm_kernel<1, 4><<<MT * 1, 256, 0, stream>>>(xh, WT, nullptr, h0, b_in,
      N, 128, 32, MT, 1);

  // ---- GAT layer 1: 128 -> 8x256 ----
  convert_wT<<<dim3(4, 64), dim3(32, 8), 0, stream>>>(W1, WT, 128, 2048);
  gemm_kernel<2, 4><<<MT * 16, 256, 0, stream>>>(h0, WT, nullptr, Hb, nullptr,
      N, 2048, 128, MT, 16);
  alpha_kernel<8, 256><<<(N * 8 + 3) / 4, 256, 0, stream>>>(Hb, as1, ad1, asrc, adst, N);
  smax_agg_kernel<8, 256, false><<<N, 256, 0, stream>>>(Hb, row_ptr, col,
      asrc, adst, b1, XB, nullptr);

  // ---- GAT layer 2: 2048 -> 8x256 ----
  convert_wT<<<dim3(64, 64), dim3(32, 8), 0, stream>>>(W2, WT, 2048, 2048);
  gemm_kernel<2, 4><<<MT * 16, 256, 0, stream>>>(XB, WT, nullptr, Hb, nullptr,
      N, 2048, 2048, MT, 16);
  alpha_kernel<8, 256><<<(N * 8 + 3) / 4, 256, 0, stream>>>(Hb, as2, ad2, asrc, adst, N);
  smax_agg_kernel<8, 256, false><<<N, 256, 0, stream>>>(Hb, row_ptr, col,
      asrc, adst, b2, XB, nullptr);

  // ---- GAT layer 3: 2048 -> 1x512 ----
  convert_wT<<<dim3(64, 16), dim3(32, 8), 0, stream>>>(W3, WT, 2048, 512);
  gemm_kernel<2, 2><<<MT * 8, 256, 0, stream>>>(XB, WT, nullptr, H3, nullptr,
      N, 512, 2048, MT, 8);
  alpha_kernel<1, 512><<<(N + 3) / 4, 256, 0, stream>>>(H3, as3, ad3, asrc, adst, N);
  smax_agg_kernel<1, 512, true><<<N, 256, 0, stream>>>(H3, row_ptr, col,
      asrc, adst, b3, nullptr, out);
}

// Round 7
// 390.060 us; speedup vs baseline: 1.2147x; 1.0051x over previous
//
#include <hip/hip_runtime.h>

typedef unsigned short u16;
typedef unsigned int u32;
typedef _Float16 f16;
typedef f16 f16x8 __attribute__((ext_vector_type(8)));
typedef float f32x4 __attribute__((ext_vector_type(4)));

__device__ __forceinline__ float h2f(f16 h){ return (float)h; }
__device__ __forceinline__ f16 f2h(float f){ return (f16)f; }

__device__ __forceinline__ f16x8 ldfrag(const f16* p){
  union { uint4 u; f16x8 h; } x;
  x.u = *(const uint4*)p;
  return x.h;
}
__device__ __forceinline__ void gload_lds16(const f16* g, f16* l){
  __builtin_amdgcn_global_load_lds(
      (const __attribute__((address_space(1))) u32*)g,
      (__attribute__((address_space(3))) u32*)l, 16, 0, 0);
}

// ---------------- CSR build ----------------

__global__ void detect_kernel(const int* __restrict__ ei, int* __restrict__ flag){
  if (threadIdx.x == 0 && blockIdx.x == 0){
    int orv = 0;
    for (int i = 0; i < 200; i++) orv |= ei[2*i + 1];
    *flag = (orv == 0) ? 1 : 0;
  }
}

__global__ void init_kernel(int* __restrict__ cnt, int* __restrict__ fillpos, int n){
  int i = blockIdx.x * blockDim.x + threadIdx.x;
  if (i < n){ cnt[i] = 1; fillpos[i] = 1; } // slot 0 = self loop
}

__global__ void count_edges(const int* __restrict__ ei, int E, const int* __restrict__ flag,
                            int* __restrict__ cnt){
  int e = blockIdx.x * blockDim.x + threadIdx.x;
  if (e >= E) return;
  int dst = (*flag) ? ei[2*E + 2*e] : ei[E + e];
  atomicAdd(&cnt[dst], 1);
}

#define SCAN_T 1024
__global__ void scan_kernel(const int* __restrict__ cnt, int* __restrict__ row_ptr, int n){
  __shared__ int sm[SCAN_T];
  int t = threadIdx.x;
  int chunk = (n + SCAN_T - 1) / SCAN_T;
  int lo = t * chunk, hi = lo + chunk; if (hi > n) hi = n; if (lo > n) lo = n;
  int s = 0;
  for (int i = lo; i < hi; i++) s += cnt[i];
  sm[t] = s; __syncthreads();
  for (int off = 1; off < SCAN_T; off <<= 1){
    int v = (t >= off) ? sm[t - off] : 0;
    __syncthreads();
    sm[t] += v;
    __syncthreads();
  }
  int base = sm[t] - s;
  for (int i = lo; i < hi; i++){ row_ptr[i] = base; base += cnt[i]; }
  if (t == 0) row_ptr[n] = sm[SCAN_T - 1];
}

__global__ void selfloop_kernel(const int* __restrict__ row_ptr, int* __restrict__ col, int n){
  int i = blockIdx.x * blockDim.x + threadIdx.x;
  if (i < n) col[row_ptr[i]] = i;
}

__global__ void fill_edges(const int* __restrict__ ei, int E, const int* __restrict__ flag,
                           const int* __restrict__ row_ptr, int* __restrict__ fillpos,
                           int* __restrict__ col){
  int e = blockIdx.x * blockDim.x + threadIdx.x;
  if (e >= E) return;
  int f = *flag;
  int src = f ? ei[2*e]       : ei[e];
  int dst = f ? ei[2*E + 2*e] : ei[E + e];
  int off = atomicAdd(&fillpos[dst], 1);
  col[row_ptr[dst] + off] = src;
}

// ---------------- converts ----------------

__global__ void convert_f16(const float* __restrict__ X, f16* __restrict__ Xo, long n){
  long i = blockIdx.x * (long)blockDim.x + threadIdx.x;
  if (i >= n) return;
  Xo[i] = f2h(X[i]);
}

// W [K][N] fp32 -> WT [N][K] fp16 (tiled transpose)
__global__ void convert_wT(const float* __restrict__ W, f16* __restrict__ T, int K, int N){
  __shared__ float sm[32][33];
  int kb = blockIdx.x * 32, nb = blockIdx.y * 32;
  int tx = threadIdx.x, ty = threadIdx.y; // (32,8)
  for (int i = 0; i < 32; i += 8)
    sm[ty + i][tx] = W[(size_t)(kb + ty + i) * N + nb + tx];
  __syncthreads();
  for (int i = 0; i < 32; i += 8)
    T[(size_t)(nb + ty + i) * K + kb + tx] = f2h(sm[tx][ty + i]);
}

// ---------------- fp16 MFMA GEMM, 2-phase double-buffered, LDS-swizzled ----
// C[M][N] = A[M][K] @ B[K][N]; A row-major fp16, B as WT[N][K] fp16.
// Tile 128 x (FJ*32); 4 waves 2x2; wave = 64 rows x FJ*16 cols; BK=32.
// LDS rows are 64B; un-swizzled fragment reads are a 4-way bank conflict
// (measured: 1.03e7 SQ_LDS_BANK_CONFLICT / 2.59e6 b128 = 4.0). Fix (rule #21,
// both-sides-or-neither with global_load_lds): physical 16B slot =
// logical slot ^ ((row>>1)&3), applied by pre-swizzling the GLOBAL source
// k-chunk on stage (LDS dest stays linear) and XORing the ds_read slot.
// EPI 0: fp32 C.  EPI 1: bias+lrelu -> fp16.  EPI 2: plain fp16.

template<int EPI, int FJ>
__global__ __launch_bounds__(256) void gemm_kernel(
    const f16* __restrict__ A, const f16* __restrict__ B,
    float* __restrict__ C, f16* __restrict__ Ch,
    const float* __restrict__ bias,
    int M, int N, int K, int nbm, int nbn)
{
  constexpr int BN = FJ * 32;
  __shared__ f16 sA[2][128 * 32];
  __shared__ f16 sB[2][BN * 32];

  // bijective XCD swizzle (m204)
  int nwg = nbm * nbn;
  int bid = blockIdx.x;
  int q = nwg >> 3, r = nwg & 7;
  int xcd = bid & 7, idx = bid >> 3;
  int wg = (xcd < r ? xcd * (q + 1) : r * (q + 1) + (xcd - r) * q) + idx;
  int bm = wg / nbn, bn = wg % nbn;

  int tid = threadIdx.x;
  int lane = tid & 63;
  int w = tid >> 6;
  int wr = (w >> 1) * 64, wc = (w & 1) * (FJ * 16);
  int lm = lane & 15;

  // pre-swizzled global k-chunk: thread t's LDS dest (row=t>>2, slot=t&3)
  // must hold logical slot (t&3)^((row>>1)&3); row>>1 bits = t>>3.
  int sk = (((tid & 3) ^ ((tid >> 3) & 3))) * 8;
  // swizzled read slot: logical slot = lane>>4; row parity bits = (lm>>1)&3
  // (row bases wr+f*16 are multiples of 16, so they don't affect (row>>1)&3).
  int phys8 = (((lane >> 4) ^ ((lm >> 1) & 3))) * 8;

  long ar0 = (long)bm * 128 + (tid >> 2);
  long ar1 = ar0 + 64;
  if (ar0 >= M) ar0 = M - 1;   // clamped rows only feed unstored outputs
  if (ar1 >= M) ar1 = M - 1;
  long br0 = (long)bn * BN + (tid >> 2);  // N multiple of BN
  long br1 = br0 + 64;                    // used only when FJ==4

  const f16* pA0 = A + ar0 * K + sk;
  const f16* pA1 = A + ar1 * K + sk;
  const f16* pB0 = B + br0 * K + sk;
  const f16* pB1 = (FJ == 4) ? (B + br1 * K + sk) : pB0;
  const int d1 = 2048;  // 64 rows * 32 elems

  auto STAGE = [&](int buf, int k0){
    gload_lds16(pA0 + k0, &sA[buf][tid * 8]);
    gload_lds16(pA1 + k0, &sA[buf][d1 + tid * 8]);
    gload_lds16(pB0 + k0, &sB[buf][tid * 8]);
    if constexpr (FJ == 4)
      gload_lds16(pB1 + k0, &sB[buf][d1 + tid * 8]);
  };

  f32x4 acc[4][FJ] = {};

  int nt = K >> 5;
  STAGE(0, 0);
  __syncthreads();          // vmcnt(0) drain + barrier: buf0 ready
  int cur = 0;
  for (int t = 0; t < nt; t++){
    if (t + 1 < nt) STAGE(cur ^ 1, (t + 1) * 32);   // overlap with compute
    f16x8 af[4], bfr[FJ];
    #pragma unroll
    for (int f = 0; f < 4; f++)
      af[f] = ldfrag(&sA[cur][(wr + f * 16 + lm) * 32 + phys8]);
    #pragma unroll
    for (int f = 0; f < FJ; f++)
      bfr[f] = ldfrag(&sB[cur][(wc + f * 16 + lm) * 32 + phys8]);
    #pragma unroll
    for (int fi = 0; fi < 4; fi++)
      #pragma unroll
      for (int fj = 0; fj < FJ; fj++)
        acc[fi][fj] = __builtin_amdgcn_mfma_f32_16x16x32_f16(af[fi], bfr[fj], acc[fi][fj], 0, 0, 0);
    __syncthreads();        // drains next-tile loads; all waves done with cur
    cur ^= 1;
  }

  // ---- store epilogue ----
  #pragma unroll
  for (int fi = 0; fi < 4; fi++){
    int mb = bm * 128 + wr + fi * 16 + ((lane >> 4) << 2);
    #pragma unroll
    for (int fj = 0; fj < FJ; fj++){
      int n = bn * BN + wc + fj * 16 + lm;
      #pragma unroll
      for (int j = 0; j < 4; j++){
        int m = mb + j;
        if (m < M){
          float v = acc[fi][fj][j];
          size_t o = (size_t)m * N + n;
          if (EPI == 0){
            C[o] = v;
          } else if (EPI == 2){
            Ch[o] = f2h(v);
          } else {
            v += bias[n];
            v = v > 0.0f ? v : 0.2f * v;
            Ch[o] = f2h(v);
          }
        }
      }
    }
  }
}

// ---------------- attention coefficients (fp16 H) ----------------

template<int HEADS, int CH>
__global__ __launch_bounds__(256) void alpha_kernel(
    const f16* __restrict__ H, const float* __restrict__ a_s, const float* __restrict__ a_d,
    float* __restrict__ asrc, float* __restrict__ adst, int Nn)
{
  int gw = blockIdx.x * 4 + (threadIdx.x >> 6);
  int lane = threadIdx.x & 63;
  int node = gw / HEADS, hd = gw % HEADS;
  if (node >= Nn) return;
  size_t base = (size_t)node * HEADS * CH + hd * CH;
  const float* asp = a_s + hd * CH;
  const float* adp = a_d + hd * CH;
  float s1 = 0.0f, s2 = 0.0f;
  #pragma unroll
  for (int i = 0; i < CH / 256; i++){
    int off = i * 256 + lane * 4;
    union { uint2 u; f16 h[4]; } x;
    x.u = *(const uint2*)(H + base + off);
    float4 s4 = *(const float4*)(asp + off);
    float4 d4 = *(const float4*)(adp + off);
    s1 += h2f(x.h[0]) * s4.x + h2f(x.h[1]) * s4.y + h2f(x.h[2]) * s4.z + h2f(x.h[3]) * s4.w;
    s2 += h2f(x.h[0]) * d4.x + h2f(x.h[1]) * d4.y + h2f(x.h[2]) * d4.z + h2f(x.h[3]) * d4.w;
  }
  for (int off = 32; off; off >>= 1){
    s1 += __shfl_xor(s1, off);
    s2 += __shfl_xor(s2, off);
  }
  if (lane == 0){ asrc[gw] = s1; adst[gw] = s2; }
}

// ---------------- fused segment-softmax + aggregation ----------------
// Block per dst node. Phase A: wave 0 computes per-head max & 1/sum.
// Phase B: all 256 threads recompute edge weights and aggregate features.

template<int HEADS, int CH, bool FINAL>
__global__ __launch_bounds__(256) void smax_agg_kernel(
    const f16* __restrict__ H, const int* __restrict__ row_ptr,
    const int* __restrict__ col,
    const float* __restrict__ asrc, const float* __restrict__ adst,
    const float* __restrict__ bias, f16* __restrict__ Oh, float* __restrict__ Ofp)
{
  constexpr int F = HEADS * CH;
  constexpr int CPT = F / 256;
  __shared__ float s_m[HEADS], s_inv[HEADS];
  int dst = blockIdx.x;
  int t = threadIdx.x;
  int s = row_ptr[dst], e = row_ptr[dst + 1];

  if (t < 64){
    const int hd = (HEADS == 8) ? (t & 7) : 0;
    const int el = (HEADS == 8) ? (t >> 3) : t;
    const int EPP = 64 / HEADS;
    float ad = adst[dst * HEADS + hd];
    float m = -1e30f;
    for (int p = s + el; p < e; p += EPP){
      float v = asrc[col[p] * HEADS + hd] + ad;
      v = v > 0.0f ? v : 0.2f * v;
      m = fmaxf(m, v);
    }
    for (int off = HEADS; off < 64; off <<= 1) m = fmaxf(m, __shfl_xor(m, off));
    float sum = 0.0f;
    for (int p = s + el; p < e; p += EPP){
      float v = asrc[col[p] * HEADS + hd] + ad;
      v = v > 0.0f ? v : 0.2f * v;
      sum += __expf(v - m);
    }
    for (int off = HEADS; off < 64; off <<= 1) sum += __shfl_xor(sum, off);
    if (el == 0){ s_m[hd] = m; s_inv[hd] = 1.0f / (sum + 1e-16f); }
  }
  __syncthreads();

  int c0 = t * CPT;
  int hd = c0 / CH;
  float m = s_m[hd], inv = s_inv[hd];
  float ad = adst[dst * HEADS + hd];
  float acc[CPT] = {};
  int p = s;

  auto wgt = [&](int src) -> float {
    float v = asrc[src * HEADS + hd] + ad;
    v = v > 0.0f ? v : 0.2f * v;
    return __expf(v - m) * inv;
  };

  for (; p + 4 <= e; p += 4){
    int i0 = col[p], i1 = col[p+1], i2 = col[p+2], i3 = col[p+3];
    if (CPT == 8){
      union { uint4 u; f16 h[8]; } x0, x1, x2, x3;
      x0.u = *(const uint4*)(H + (size_t)i0 * F + c0);
      x1.u = *(const uint4*)(H + (size_t)i1 * F + c0);
      x2.u = *(const uint4*)(H + (size_t)i2 * F + c0);
      x3.u = *(const uint4*)(H + (size_t)i3 * F + c0);
      float w0 = wgt(i0), w1 = wgt(i1), w2 = wgt(i2), w3 = wgt(i3);
      #pragma unroll
      for (int i = 0; i < 8; i++)
        acc[i] += w0 * h2f(x0.h[i]) + w1 * h2f(x1.h[i])
                + w2 * h2f(x2.h[i]) + w3 * h2f(x3.h[i]);
    } else {
      union { u32 u; f16 h[2]; } x0, x1, x2, x3;
      x0.u = *(const u32*)(H + (size_t)i0 * F + c0);
      x1.u = *(const u32*)(H + (size_t)i1 * F + c0);
      x2.u = *(const u32*)(H + (size_t)i2 * F + c0);
      x3.u = *(const u32*)(H + (size_t)i3 * F + c0);
      float w0 = wgt(i0), w1 = wgt(i1), w2 = wgt(i2), w3 = wgt(i3);
      acc[0] += w0 * h2f(x0.h[0]) + w1 * h2f(x1.h[0]) + w2 * h2f(x2.h[0]) + w3 * h2f(x3.h[0]);
      acc[1] += w0 * h2f(x0.h[1]) + w1 * h2f(x1.h[1]) + w2 * h2f(x2.h[1]) + w3 * h2f(x3.h[1]);
    }
  }
  for (; p < e; p++){
    int src = col[p];
    float w0 = wgt(src);
    if (CPT == 8){
      union { uint4 u; f16 h[8]; } x;
      x.u = *(const uint4*)(H + (size_t)src * F + c0);
      #pragma unroll
      for (int i = 0; i < 8; i++) acc[i] += w0 * h2f(x.h[i]);
    } else {
      union { u32 u; f16 h[2]; } x;
      x.u = *(const u32*)(H + (size_t)src * F + c0);
      acc[0] += w0 * h2f(x.h[0]); acc[1] += w0 * h2f(x.h[1]);
    }
  }

  #pragma unroll
  for (int i = 0; i < CPT; i++){
    float v = acc[i] + bias[c0 + i];
    v = v > 0.0f ? v : 0.2f * v;
    size_t o = (size_t)dst * F + c0 + i;
    if (FINAL) Ofp[o] = v;
    else       Oh[o]  = f2h(v);
  }
}

// ---------------- launcher ----------------

extern "C" void kernel_launch(void* const* d_in, const int* in_sizes, int n_in,
                              void* d_out, int out_size, void* d_ws, size_t ws_size,
                              hipStream_t stream)
{
  const float* x    = (const float*)d_in[0];
  const int*   ei   = (const int*)d_in[1];
  const float* W_in = (const float*)d_in[2];
  const float* b_in = (const float*)d_in[3];
  const float* W1   = (const float*)d_in[4];
  const float* as1  = (const float*)d_in[5];
  const float* ad1  = (const float*)d_in[6];
  const float* b1   = (const float*)d_in[7];
  const float* W2   = (const float*)d_in[8];
  const float* as2  = (const float*)d_in[9];
  const float* ad2  = (const float*)d_in[10];
  const float* b2   = (const float*)d_in[11];
  const float* W3   = (const float*)d_in[12];
  const float* as3  = (const float*)d_in[13];
  const float* ad3  = (const float*)d_in[14];
  const float* b3   = (const float*)d_in[15];

  const int N  = in_sizes[0] / 32;   // 10000
  const int E  = in_sizes[1] / 2;    // 80000
  const int ET = E + N;

  char* w = (char*)d_ws;
  size_t off = 0;
  auto carve = [&](size_t bytes) -> char* {
    off = (off + 255) & ~(size_t)255;
    char* p = w + off;
    off += bytes;
    return p;
  };

  int* flag    = (int*)carve(4);
  int* cnt     = (int*)carve((size_t)N * 4);
  int* fillpos = (int*)carve((size_t)N * 4);
  int* row_ptr = (int*)carve((size_t)(N + 1) * 4);
  int* col     = (int*)carve((size_t)ET * 4);
  f16* xh      = (f16*)carve((size_t)N * 32 * 2);
  f16* h0      = (f16*)carve((size_t)N * 128 * 2);
  f16* WT      = (f16*)carve((size_t)2048 * 2048 * 2);
  f16* Hb      = (f16*)carve((size_t)N * 2048 * 2);   // fp16 h for layers 1,2
  f16* H3      = (f16*)carve((size_t)N * 512 * 2);    // fp16 h for layer 3
  f16* XB      = (f16*)carve((size_t)N * 2048 * 2);
  float* asrc  = (float*)carve((size_t)N * 8 * 4);
  float* adst  = (float*)carve((size_t)N * 8 * 4);

  if (off > ws_size) return;

  const int MT = (N + 127) / 128;   // 79 row-tiles
  float* out = (float*)d_out;

  // CSR build
  detect_kernel<<<1, 1, 0, stream>>>(ei, flag);
  init_kernel<<<(N + 255) / 256, 256, 0, stream>>>(cnt, fillpos, N);
  count_edges<<<(E + 255) / 256, 256, 0, stream>>>(ei, E, flag, cnt);
  scan_kernel<<<1, SCAN_T, 0, stream>>>(cnt, row_ptr, N);
  selfloop_kernel<<<(N + 255) / 256, 256, 0, stream>>>(row_ptr, col, N);
  fill_edges<<<(E + 255) / 256, 256, 0, stream>>>(ei, E, flag, row_ptr, fillpos, col);

  // input projection: h0 = lrelu(x @ W_in + b_in) -> fp16
  convert_f16<<<((long)N * 32 + 255) / 256, 256, 0, stream>>>(x, xh, (long)N * 32);
  convert_wT<<<dim3(1, 4), dim3(32, 8), 0, stream>>>(W_in, WT, 32, 128);
  gemm_kernel<1, 4><<<MT * 1, 256, 0, stream>>>(xh, WT, nullptr, h0, b_in,
      N, 128, 32, MT, 1);

  // ---- GAT layer 1: 128 -> 8x256 ----
  convert_wT<<<dim3(4, 64), dim3(32, 8), 0, stream>>>(W1, WT, 128, 2048);
  gemm_kernel<2, 4><<<MT * 16, 256, 0, stream>>>(h0, WT, nullptr, Hb, nullptr,
      N, 2048, 128, MT, 16);
  alpha_kernel<8, 256><<<(N * 8 + 3) / 4, 256, 0, stream>>>(Hb, as1, ad1, asrc, adst, N);
  smax_agg_kernel<8, 256, false><<<N, 256, 0, stream>>>(Hb, row_ptr, col,
      asrc, adst, b1, XB, nullptr);

  // ---- GAT layer 2: 2048 -> 8x256 ----
  convert_wT<<<dim3(64, 64), dim3(32, 8), 0, stream>>>(W2, WT, 2048, 2048);
  gemm_kernel<2, 4><<<MT * 16, 256, 0, stream>>>(XB, WT, nullptr, Hb, nullptr,
      N, 2048, 2048, MT, 16);
  alpha_kernel<8, 256><<<(N * 8 + 3) / 4, 256, 0, stream>>>(Hb, as2, ad2, asrc, adst, N);
  smax_agg_kernel<8, 256, false><<<N, 256, 0, stream>>>(Hb, row_ptr, col,
      asrc, adst, b2, XB, nullptr);

  // ---- GAT layer 3: 2048 -> 1x512 ----
  convert_wT<<<dim3(64, 16), dim3(32, 8), 0, stream>>>(W3, WT, 2048, 512);
  gemm_kernel<2, 2><<<MT * 8, 256, 0, stream>>>(XB, WT, nullptr, H3, nullptr,
      N, 512, 2048, MT, 8);
  alpha_kernel<1, 512><<<(N + 3) / 4, 256, 0, stream>>>(H3, as3, ad3, asrc, adst, N);
  smax_agg_kernel<1, 512, true><<<N, 256, 0, stream>>>(H3, row_ptr, col,
      asrc, adst, b3, nullptr, out);
}

// Round 8
// 372.372 us; speedup vs baseline: 1.2724x; 1.0475x over previous
//
#include <hip/hip_runtime.h>

typedef unsigned short u16;
typedef unsigned int u32;
typedef _Float16 f16;
typedef f16 f16x8 __attribute__((ext_vector_type(8)));
typedef float f32x4 __attribute__((ext_vector_type(4)));

__device__ __forceinline__ float h2f(f16 h){ return (float)h; }
__device__ __forceinline__ f16 f2h(float f){ return (f16)f; }

__device__ __forceinline__ f16x8 ldfrag(const f16* p){
  union { uint4 u; f16x8 h; } x;
  x.u = *(const uint4*)p;
  return x.h;
}
__device__ __forceinline__ void gload_lds16(const f16* g, f16* l){
  __builtin_amdgcn_global_load_lds(
      (const __attribute__((address_space(1))) u32*)g,
      (__attribute__((address_space(3))) u32*)l, 16, 0, 0);
}

// ---------------- CSR build ----------------

__global__ void detect_kernel(const int* __restrict__ ei, int* __restrict__ flag){
  if (threadIdx.x == 0 && blockIdx.x == 0){
    int orv = 0;
    for (int i = 0; i < 200; i++) orv |= ei[2*i + 1];
    *flag = (orv == 0) ? 1 : 0;
  }
}

__global__ void init_kernel(int* __restrict__ cnt, int* __restrict__ fillpos, int n){
  int i = blockIdx.x * blockDim.x + threadIdx.x;
  if (i < n){ cnt[i] = 1; fillpos[i] = 1; } // slot 0 = self loop
}

__global__ void count_edges(const int* __restrict__ ei, int E, const int* __restrict__ flag,
                            int* __restrict__ cnt){
  int e = blockIdx.x * blockDim.x + threadIdx.x;
  if (e >= E) return;
  int dst = (*flag) ? ei[2*E + 2*e] : ei[E + e];
  atomicAdd(&cnt[dst], 1);
}

#define SCAN_T 1024
__global__ void scan_kernel(const int* __restrict__ cnt, int* __restrict__ row_ptr, int n){
  __shared__ int sm[SCAN_T];
  int t = threadIdx.x;
  int chunk = (n + SCAN_T - 1) / SCAN_T;
  int lo = t * chunk, hi = lo + chunk; if (hi > n) hi = n; if (lo > n) lo = n;
  int s = 0;
  for (int i = lo; i < hi; i++) s += cnt[i];
  sm[t] = s; __syncthreads();
  for (int off = 1; off < SCAN_T; off <<= 1){
    int v = (t >= off) ? sm[t - off] : 0;
    __syncthreads();
    sm[t] += v;
    __syncthreads();
  }
  int base = sm[t] - s;
  for (int i = lo; i < hi; i++){ row_ptr[i] = base; base += cnt[i]; }
  if (t == 0) row_ptr[n] = sm[SCAN_T - 1];
}

__global__ void selfloop_kernel(const int* __restrict__ row_ptr, int* __restrict__ col, int n){
  int i = blockIdx.x * blockDim.x + threadIdx.x;
  if (i < n) col[row_ptr[i]] = i;
}

__global__ void fill_edges(const int* __restrict__ ei, int E, const int* __restrict__ flag,
                           const int* __restrict__ row_ptr, int* __restrict__ fillpos,
                           int* __restrict__ col){
  int e = blockIdx.x * blockDim.x + threadIdx.x;
  if (e >= E) return;
  int f = *flag;
  int src = f ? ei[2*e]       : ei[e];
  int dst = f ? ei[2*E + 2*e] : ei[E + e];
  int off = atomicAdd(&fillpos[dst], 1);
  col[row_ptr[dst] + off] = src;
}

// ---------------- converts ----------------

__global__ void convert_f16(const float* __restrict__ X, f16* __restrict__ Xo, long n){
  long i = blockIdx.x * (long)blockDim.x + threadIdx.x;
  if (i >= n) return;
  Xo[i] = f2h(X[i]);
}

// W [K][N] fp32 -> WT [N][K] fp16 (tiled transpose)
__global__ void convert_wT(const float* __restrict__ W, f16* __restrict__ T, int K, int N){
  __shared__ float sm[32][33];
  int kb = blockIdx.x * 32, nb = blockIdx.y * 32;
  int tx = threadIdx.x, ty = threadIdx.y; // (32,8)
  for (int i = 0; i < 32; i += 8)
    sm[ty + i][tx] = W[(size_t)(kb + ty + i) * N + nb + tx];
  __syncthreads();
  for (int i = 0; i < 32; i += 8)
    T[(size_t)(nb + ty + i) * K + kb + tx] = f2h(sm[tx][ty + i]);
}

// ---------------- fp16 MFMA GEMM, dbuf, BK templated, LDS-swizzled --------
// C[M][N] = A[M][K] @ B[K][N]; A row-major fp16 (M padded to x128), B WT[N][K].
// Tile 128 x (FJ*32); 4 waves 2x2; BK=64 normally (32 for the K=32 layer).
// Per K-step: stage next tile (gload_lds, pre-swizzled global src), ds_read
// swizzled frags, BK/32 x 4 x FJ MFMA under setprio(1), one barrier.
// Swizzle (both-sides, rule #21): phys 16B slot = logical ^ swz(row),
//   BK=64: swz = row&7 (8 slots/row);  BK=32: swz = (row>>1)&3 (verified R7).
// EPI 0: fp32 C.  EPI 1: bias+lrelu -> fp16.  EPI 2: plain fp16.

template<int EPI, int FJ, int BK>
__global__ __launch_bounds__(256) void gemm_kernel(
    const f16* __restrict__ A, const f16* __restrict__ B,
    float* __restrict__ C, f16* __restrict__ Ch,
    const float* __restrict__ bias,
    int M, int N, int K, int nbm, int nbn)
{
  constexpr int BN  = FJ * 32;
  constexpr int TPR = BK / 8;        // 16B chunks per LDS row
  constexpr int RPG = 256 / TPR;     // rows covered per gload_lds call
  constexpr int NGA = 128 / RPG;     // gloads for A tile
  constexpr int NGB = BN / RPG;      // gloads for B tile
  constexpr int KS  = BK / 32;       // k-slices per step

  __shared__ f16 sA[2][128 * BK];
  __shared__ f16 sB[2][BN * BK];

  // bijective XCD swizzle (m204)
  int nwg = nbm * nbn;
  int bid = blockIdx.x;
  int q = nwg >> 3, r = nwg & 7;
  int xcd = bid & 7, idx = bid >> 3;
  int wg = (xcd < r ? xcd * (q + 1) : r * (q + 1) + (xcd - r) * q) + idx;
  int bm = wg / nbn, bn = wg % nbn;

  int tid = threadIdx.x;
  int lane = tid & 63;
  int w = tid >> 6;
  int wr = (w >> 1) * 64, wc = (w & 1) * (FJ * 16);
  int lm = lane & 15;

  // staging: thread covers row rg (+RPG*i), phys slot tid%TPR holding
  // pre-swizzled logical chunk sk.
  int slot = tid % TPR, rg = tid / TPR;
  int sk;
  if constexpr (BK == 64) sk = ((slot ^ (rg & 7))) * 8;
  else                    sk = ((slot ^ ((rg >> 1) & 3))) * 8;

  const f16* pA[NGA];
  const f16* pB[NGB];
  #pragma unroll
  for (int i = 0; i < NGA; i++)
    pA[i] = A + ((long)bm * 128 + rg + RPG * i) * K + sk;
  #pragma unroll
  for (int i = 0; i < NGB; i++)
    pB[i] = B + ((long)bn * BN + rg + RPG * i) * K + sk;

  auto STAGE = [&](int buf, int k0){
    #pragma unroll
    for (int i = 0; i < NGA; i++)
      gload_lds16(pA[i] + k0, &sA[buf][i * 2048 + tid * 8]);
    #pragma unroll
    for (int i = 0; i < NGB; i++)
      gload_lds16(pB[i] + k0, &sB[buf][i * 2048 + tid * 8]);
  };

  f32x4 acc[4][FJ] = {};

  int nt = K / BK;
  STAGE(0, 0);
  __syncthreads();          // vmcnt(0) drain + barrier: buf0 ready
  int cur = 0;
  for (int t = 0; t < nt; t++){
    if (t + 1 < nt) STAGE(cur ^ 1, (t + 1) * BK);   // overlap with compute
    f16x8 af[4][KS], bfr[FJ][KS];
    #pragma unroll
    for (int ks = 0; ks < KS; ks++){
      #pragma unroll
      for (int f = 0; f < 4; f++){
        int row = wr + f * 16 + lm;
        int phys;
        if constexpr (BK == 64) phys = (ks * 4 + (lane >> 4)) ^ (lm & 7);
        else                    phys = (lane >> 4) ^ ((lm >> 1) & 3);
        af[f][ks] = ldfrag(&sA[cur][row * BK + phys * 8]);
      }
      #pragma unroll
      for (int f = 0; f < FJ; f++){
        int row = wc + f * 16 + lm;
        int phys;
        if constexpr (BK == 64) phys = (ks * 4 + (lane >> 4)) ^ (lm & 7);
        else                    phys = (lane >> 4) ^ ((lm >> 1) & 3);
        bfr[f][ks] = ldfrag(&sB[cur][row * BK + phys * 8]);
      }
    }
    __builtin_amdgcn_s_setprio(1);
    #pragma unroll
    for (int ks = 0; ks < KS; ks++)
      #pragma unroll
      for (int fi = 0; fi < 4; fi++)
        #pragma unroll
        for (int fj = 0; fj < FJ; fj++)
          acc[fi][fj] = __builtin_amdgcn_mfma_f32_16x16x32_f16(
              af[fi][ks], bfr[fj][ks], acc[fi][fj], 0, 0, 0);
    __builtin_amdgcn_s_setprio(0);
    __syncthreads();        // drains next-tile loads; all waves done with cur
    cur ^= 1;
  }

  // ---- store epilogue (M padded to multiple of 128: no guards) ----
  #pragma unroll
  for (int fi = 0; fi < 4; fi++){
    int mb = bm * 128 + wr + fi * 16 + ((lane >> 4) << 2);
    #pragma unroll
    for (int fj = 0; fj < FJ; fj++){
      int n = bn * BN + wc + fj * 16 + lm;
      #pragma unroll
      for (int j = 0; j < 4; j++){
        int m = mb + j;
        float v = acc[fi][fj][j];
        size_t o = (size_t)m * N + n;
        if (EPI == 0){
          C[o] = v;
        } else if (EPI == 2){
          Ch[o] = f2h(v);
        } else {
          v += bias[n];
          v = v > 0.0f ? v : 0.2f * v;
          Ch[o] = f2h(v);
        }
      }
    }
  }
}

// ---------------- attention coefficients (fp16 H) ----------------

template<int HEADS, int CH>
__global__ __launch_bounds__(256) void alpha_kernel(
    const f16* __restrict__ H, const float* __restrict__ a_s, const float* __restrict__ a_d,
    float* __restrict__ asrc, float* __restrict__ adst, int Nn)
{
  int gw = blockIdx.x * 4 + (threadIdx.x >> 6);
  int lane = threadIdx.x & 63;
  int node = gw / HEADS, hd = gw % HEADS;
  if (node >= Nn) return;
  size_t base = (size_t)node * HEADS * CH + hd * CH;
  const float* asp = a_s + hd * CH;
  const float* adp = a_d + hd * CH;
  float s1 = 0.0f, s2 = 0.0f;
  #pragma unroll
  for (int i = 0; i < CH / 256; i++){
    int off = i * 256 + lane * 4;
    union { uint2 u; f16 h[4]; } x;
    x.u = *(const uint2*)(H + base + off);
    float4 s4 = *(const float4*)(asp + off);
    float4 d4 = *(const float4*)(adp + off);
    s1 += h2f(x.h[0]) * s4.x + h2f(x.h[1]) * s4.y + h2f(x.h[2]) * s4.z + h2f(x.h[3]) * s4.w;
    s2 += h2f(x.h[0]) * d4.x + h2f(x.h[1]) * d4.y + h2f(x.h[2]) * d4.z + h2f(x.h[3]) * d4.w;
  }
  for (int off = 32; off; off >>= 1){
    s1 += __shfl_xor(s1, off);
    s2 += __shfl_xor(s2, off);
  }
  if (lane == 0){ asrc[gw] = s1; adst[gw] = s2; }
}

// ---------------- fused segment-softmax + aggregation ----------------

template<int HEADS, int CH, bool FINAL>
__global__ __launch_bounds__(256) void smax_agg_kernel(
    const f16* __restrict__ H, const int* __restrict__ row_ptr,
    const int* __restrict__ col,
    const float* __restrict__ asrc, const float* __restrict__ adst,
    const float* __restrict__ bias, f16* __restrict__ Oh, float* __restrict__ Ofp)
{
  constexpr int F = HEADS * CH;
  constexpr int CPT = F / 256;
  __shared__ float s_m[HEADS], s_inv[HEADS];
  int dst = blockIdx.x;
  int t = threadIdx.x;
  int s = row_ptr[dst], e = row_ptr[dst + 1];

  if (t < 64){
    const int hd = (HEADS == 8) ? (t & 7) : 0;
    const int el = (HEADS == 8) ? (t >> 3) : t;
    const int EPP = 64 / HEADS;
    float ad = adst[dst * HEADS + hd];
    float m = -1e30f;
    for (int p = s + el; p < e; p += EPP){
      float v = asrc[col[p] * HEADS + hd] + ad;
      v = v > 0.0f ? v : 0.2f * v;
      m = fmaxf(m, v);
    }
    for (int off = HEADS; off < 64; off <<= 1) m = fmaxf(m, __shfl_xor(m, off));
    float sum = 0.0f;
    for (int p = s + el; p < e; p += EPP){
      float v = asrc[col[p] * HEADS + hd] + ad;
      v = v > 0.0f ? v : 0.2f * v;
      sum += __expf(v - m);
    }
    for (int off = HEADS; off < 64; off <<= 1) sum += __shfl_xor(sum, off);
    if (el == 0){ s_m[hd] = m; s_inv[hd] = 1.0f / (sum + 1e-16f); }
  }
  __syncthreads();

  int c0 = t * CPT;
  int hd = c0 / CH;
  float m = s_m[hd], inv = s_inv[hd];
  float ad = adst[dst * HEADS + hd];
  float acc[CPT] = {};
  int p = s;

  auto wgt = [&](int src) -> float {
    float v = asrc[src * HEADS + hd] + ad;
    v = v > 0.0f ? v : 0.2f * v;
    return __expf(v - m) * inv;
  };

  for (; p + 4 <= e; p += 4){
    int i0 = col[p], i1 = col[p+1], i2 = col[p+2], i3 = col[p+3];
    if (CPT == 8){
      union { uint4 u; f16 h[8]; } x0, x1, x2, x3;
      x0.u = *(const uint4*)(H + (size_t)i0 * F + c0);
      x1.u = *(const uint4*)(H + (size_t)i1 * F + c0);
      x2.u = *(const uint4*)(H + (size_t)i2 * F + c0);
      x3.u = *(const uint4*)(H + (size_t)i3 * F + c0);
      float w0 = wgt(i0), w1 = wgt(i1), w2 = wgt(i2), w3 = wgt(i3);
      #pragma unroll
      for (int i = 0; i < 8; i++)
        acc[i] += w0 * h2f(x0.h[i]) + w1 * h2f(x1.h[i])
                + w2 * h2f(x2.h[i]) + w3 * h2f(x3.h[i]);
    } else {
      union { u32 u; f16 h[2]; } x0, x1, x2, x3;
      x0.u = *(const u32*)(H + (size_t)i0 * F + c0);
      x1.u = *(const u32*)(H + (size_t)i1 * F + c0);
      x2.u = *(const u32*)(H + (size_t)i2 * F + c0);
      x3.u = *(const u32*)(H + (size_t)i3 * F + c0);
      float w0 = wgt(i0), w1 = wgt(i1), w2 = wgt(i2), w3 = wgt(i3);
      acc[0] += w0 * h2f(x0.h[0]) + w1 * h2f(x1.h[0]) + w2 * h2f(x2.h[0]) + w3 * h2f(x3.h[0]);
      acc[1] += w0 * h2f(x0.h[1]) + w1 * h2f(x1.h[1]) + w2 * h2f(x2.h[1]) + w3 * h2f(x3.h[1]);
    }
  }
  for (; p < e; p++){
    int src = col[p];
    float w0 = wgt(src);
    if (CPT == 8){
      union { uint4 u; f16 h[8]; } x;
      x.u = *(const uint4*)(H + (size_t)src * F + c0);
      #pragma unroll
      for (int i = 0; i < 8; i++) acc[i] += w0 * h2f(x.h[i]);
    } else {
      union { u32 u; f16 h[2]; } x;
      x.u = *(const u32*)(H + (size_t)src * F + c0);
      acc[0] += w0 * h2f(x.h[0]); acc[1] += w0 * h2f(x.h[1]);
    }
  }

  #pragma unroll
  for (int i = 0; i < CPT; i++){
    float v = acc[i] + bias[c0 + i];
    v = v > 0.0f ? v : 0.2f * v;
    size_t o = (size_t)dst * F + c0 + i;
    if (FINAL) Ofp[o] = v;
    else       Oh[o]  = f2h(v);
  }
}

// ---------------- launcher ----------------

extern "C" void kernel_launch(void* const* d_in, const int* in_sizes, int n_in,
                              void* d_out, int out_size, void* d_ws, size_t ws_size,
                              hipStream_t stream)
{
  const float* x    = (const float*)d_in[0];
  const int*   ei   = (const int*)d_in[1];
  const float* W_in = (const float*)d_in[2];
  const float* b_in = (const float*)d_in[3];
  const float* W1   = (const float*)d_in[4];
  const float* as1  = (const float*)d_in[5];
  const float* ad1  = (const float*)d_in[6];
  const float* b1   = (const float*)d_in[7];
  const float* W2   = (const float*)d_in[8];
  const float* as2  = (const float*)d_in[9];
  const float* ad2  = (const float*)d_in[10];
  const float* b2   = (const float*)d_in[11];
  const float* W3   = (const float*)d_in[12];
  const float* as3  = (const float*)d_in[13];
  const float* ad3  = (const float*)d_in[14];
  const float* b3   = (const float*)d_in[15];

  const int N  = in_sizes[0] / 32;   // 10000
  const int E  = in_sizes[1] / 2;    // 80000
  const int ET = E + N;
  const int MT = (N + 127) / 128;    // 79 row-tiles
  const int MP = MT * 128;           // 10112: padded rows (garbage rows are
                                     // deterministic, finite, never read)

  char* w = (char*)d_ws;
  size_t off = 0;
  auto carve = [&](size_t bytes) -> char* {
    off = (off + 255) & ~(size_t)255;
    char* p = w + off;
    off += bytes;
    return p;
  };

  int* flag    = (int*)carve(4);
  int* cnt     = (int*)carve((size_t)N * 4);
  int* fillpos = (int*)carve((size_t)N * 4);
  int* row_ptr = (int*)carve((size_t)(N + 1) * 4);
  int* col     = (int*)carve((size_t)ET * 4);
  f16* xh      = (f16*)carve((size_t)MP * 32 * 2);
  f16* h0      = (f16*)carve((size_t)MP * 128 * 2);
  f16* WT      = (f16*)carve((size_t)2048 * 2048 * 2);
  f16* Hb      = (f16*)carve((size_t)MP * 2048 * 2);
  f16* H3      = (f16*)carve((size_t)MP * 512 * 2);
  f16* XB      = (f16*)carve((size_t)MP * 2048 * 2);
  float* asrc  = (float*)carve((size_t)N * 8 * 4);
  float* adst  = (float*)carve((size_t)N * 8 * 4);

  if (off > ws_size) return;

  float* out = (float*)d_out;

  // CSR build
  detect_kernel<<<1, 1, 0, stream>>>(ei, flag);
  init_kernel<<<(N + 255) / 256, 256, 0, stream>>>(cnt, fillpos, N);
  count_edges<<<(E + 255) / 256, 256, 0, stream>>>(ei, E, flag, cnt);
  scan_kernel<<<1, SCAN_T, 0, stream>>>(cnt, row_ptr, N);
  selfloop_kernel<<<(N + 255) / 256, 256, 0, stream>>>(row_ptr, col, N);
  fill_edges<<<(E + 255) / 256, 256, 0, stream>>>(ei, E, flag, row_ptr, fillpos, col);

  // input projection: h0 = lrelu(x @ W_in + b_in) -> fp16  (K=32 -> BK=32)
  convert_f16<<<((long)N * 32 + 255) / 256, 256, 0, stream>>>(x, xh, (long)N * 32);
  convert_wT<<<dim3(1, 4), dim3(32, 8), 0, stream>>>(W_in, WT, 32, 128);
  gemm_kernel<1, 4, 32><<<MT * 1, 256, 0, stream>>>(xh, WT, nullptr, h0, b_in,
      MP, 128, 32, MT, 1);

  // ---- GAT layer 1: 128 -> 8x256 ----
  convert_wT<<<dim3(4, 64), dim3(32, 8), 0, stream>>>(W1, WT, 128, 2048);
  gemm_kernel<2, 4, 64><<<MT * 16, 256, 0, stream>>>(h0, WT, nullptr, Hb, nullptr,
      MP, 2048, 128, MT, 16);
  alpha_kernel<8, 256><<<(N * 8 + 3) / 4, 256, 0, stream>>>(Hb, as1, ad1, asrc, adst, N);
  smax_agg_kernel<8, 256, false><<<N, 256, 0, stream>>>(Hb, row_ptr, col,
      asrc, adst, b1, XB, nullptr);

  // ---- GAT layer 2: 2048 -> 8x256 ----
  convert_wT<<<dim3(64, 64), dim3(32, 8), 0, stream>>>(W2, WT, 2048, 2048);
  gemm_kernel<2, 4, 64><<<MT * 16, 256, 0, stream>>>(XB, WT, nullptr, Hb, nullptr,
      MP, 2048, 2048, MT, 16);
  alpha_kernel<8, 256><<<(N * 8 + 3) / 4, 256, 0, stream>>>(Hb, as2, ad2, asrc, adst, N);
  smax_agg_kernel<8, 256, false><<<N, 256, 0, stream>>>(Hb, row_ptr, col,
      asrc, adst, b2, XB, nullptr);

  // ---- GAT layer 3: 2048 -> 1x512 ----
  convert_wT<<<dim3(64, 16), dim3(32, 8), 0, stream>>>(W3, WT, 2048, 512);
  gemm_kernel<2, 2, 64><<<MT * 8, 256, 0, stream>>>(XB, WT, nullptr, H3, nullptr,
      MP, 512, 2048, MT, 8);
  alpha_kernel<1, 512><<<(N + 3) / 4, 256, 0, stream>>>(H3, as3, ad3, asrc, adst, N);
  smax_agg_kernel<1, 512, true><<<N, 256, 0, stream>>>(H3, row_ptr, col,
      asrc, adst, b3, nullptr, out);
}